// Round 2
// baseline (2134.407 us; speedup 1.0000x reference)
//
#include <hip/hip_runtime.h>

#define NN 50000
#define NE 800000
#define NG 256
#define BN_EPS 1e-5f

typedef __attribute__((ext_vector_type(8))) short short8v;
typedef __attribute__((ext_vector_type(4))) float f32x4;

__device__ __forceinline__ float sigm(float x) { return 1.0f / (1.0f + __expf(-x)); }
__device__ __forceinline__ float sofp(float x) { return fmaxf(x, 0.0f) + __logf(1.0f + __expf(-fabsf(x))); }

__device__ __forceinline__ short f2bf(float f) {
    union { float f; unsigned u; } a; a.f = f;
    unsigned r = a.u + 0x7FFFu + ((a.u >> 16) & 1u);
    return (short)(r >> 16);
}
__device__ __forceinline__ float bf2f(short h) {
    union { unsigned u; float f; } a; a.u = ((unsigned)(unsigned short)h) << 16;
    return a.f;
}

// ---------------- node linear ----------------
// blockIdx.y = m: 0: Tdst f-part = x@Wf[0:128]   + bf
//                 1: Tsrc f-part = x@Wf[128:256]
//                 2: Tdst s-part = x@Ws[0:128]   + bs
//                 3: Tsrc s-part = x@Ws[128:256]
// Tables interleaved: T[n][2*c+0]=f-part, T[n][2*c+1]=s-part (256 f32/row)
__global__ __launch_bounds__(256) void k_node_linear(
    const float* __restrict__ x,
    const float* __restrict__ Wf, const float* __restrict__ Ws,
    const float* __restrict__ bf, const float* __restrict__ bs,
    float* __restrict__ Tdst, float* __restrict__ Tsrc)
{
    const int m = blockIdx.y;
    const int n0 = blockIdx.x * 64;
    const int tid = threadIdx.x;
    const int tx = tid & 15;   // channel group (8 ch each)
    const int ty = tid >> 4;   // node group (4 nodes each)
    const float* W = ((m & 2) ? Ws : Wf) + (size_t)(m & 1) * 128 * 128;

    __shared__ float As[16][64];
    __shared__ float Bs[16][128];

    float acc[4][8];
#pragma unroll
    for (int i = 0; i < 4; ++i)
#pragma unroll
        for (int j = 0; j < 8; ++j) acc[i][j] = 0.0f;

    const int lr = tid >> 2;        // 0..63 node row for A load
    const int lq = tid & 3;         // float4 group within 16 k's
    const int br = tid >> 5;        // 0..7 k-row for B load
    const int bc = (tid & 31) * 4;  // col for B load

    for (int kc = 0; kc < 128; kc += 16) {
        float4 av = make_float4(0.f, 0.f, 0.f, 0.f);
        if (n0 + lr < NN) av = *(const float4*)(x + (size_t)(n0 + lr) * 128 + kc + lq * 4);
        const float4 b0 = *(const float4*)(W + (size_t)(kc + br) * 128 + bc);
        const float4 b1 = *(const float4*)(W + (size_t)(kc + br + 8) * 128 + bc);
        __syncthreads();
        As[lq * 4 + 0][lr] = av.x;
        As[lq * 4 + 1][lr] = av.y;
        As[lq * 4 + 2][lr] = av.z;
        As[lq * 4 + 3][lr] = av.w;
        *(float4*)&Bs[br][bc] = b0;
        *(float4*)&Bs[br + 8][bc] = b1;
        __syncthreads();
#pragma unroll
        for (int k = 0; k < 16; ++k) {
            float a[4], b[8];
#pragma unroll
            for (int i = 0; i < 4; ++i) a[i] = As[k][ty * 4 + i];
            const float4 q0 = *(const float4*)&Bs[k][tx * 8];
            const float4 q1 = *(const float4*)&Bs[k][tx * 8 + 4];
            b[0] = q0.x; b[1] = q0.y; b[2] = q0.z; b[3] = q0.w;
            b[4] = q1.x; b[5] = q1.y; b[6] = q1.z; b[7] = q1.w;
#pragma unroll
            for (int i = 0; i < 4; ++i)
#pragma unroll
                for (int j = 0; j < 8; ++j) acc[i][j] = fmaf(a[i], b[j], acc[i][j]);
        }
    }

    const float* bias = (m == 0) ? bf : ((m == 2) ? bs : nullptr);
    float bv[8];
#pragma unroll
    for (int j = 0; j < 8; ++j) bv[j] = bias ? bias[tx * 8 + j] : 0.0f;
    float* outb = ((m & 1) ? Tsrc : Tdst) + ((m >> 1) & 1);  // s-part at odd slots
#pragma unroll
    for (int i = 0; i < 4; ++i) {
        const int n = n0 + ty * 4 + i;
        if (n < NN) {
            float* p = outb + (size_t)n * 256 + tx * 16;
#pragma unroll
            for (int j = 0; j < 8; ++j) p[j * 2] = acc[i][j] + bv[j];
        }
    }
}

// ---------------- fused edge kernel (MFMA) ----------------
// Per wave: 16-edge tile. F/S = ea@We (MFMA, bf16 hi/lo x W bf16) + gathered
// node tables (fp32); msg = sigm(F)*sofp(S); atomicAdd into xout[dst].
__global__ __launch_bounds__(256, 4) void k_edge2(
    const float* __restrict__ Tdst, const float* __restrict__ Tsrc,
    const float* __restrict__ Wf, const float* __restrict__ Ws,
    const int* __restrict__ ei, const float* __restrict__ ea,
    float* __restrict__ xout)
{
    // Wt[row=ch (0:128 f, 128:256 s)][k=0..63] bf16, XOR-swizzled rows (32 KB)
    __shared__ short Wt[256 * 64];
    const int tid = threadIdx.x;
    for (int idx = tid; idx < 16384; idx += 256) {
        const int m = idx >> 13;          // 0=f, 1=s
        const int kk = (idx >> 7) & 63;
        const int ch = idx & 127;
        const float w = (m ? Ws : Wf)[(size_t)(256 + kk) * 128 + ch];
        const int row = m * 128 + ch;
        const int bcol = (kk * 2) ^ ((row & 7) << 4);
        *(short*)((char*)Wt + row * 128 + bcol) = f2bf(w);
    }
    __syncthreads();

    const int lane = tid & 63;
    const int ln = lane & 15;      // A-row (edge) / B-row (channel) index
    const int lg = lane >> 4;      // k-octet group
    const int gw = blockIdx.x * 4 + (tid >> 6);
    const int nw = gridDim.x * 4;
    const int sw = (ln & 7) << 4;  // read-side swizzle (row&7 == ln&7 for all nt)

    for (int chk = gw; chk < NE / 16; chk += nw) {
        const int e0 = chk * 16;

        // edge ids for epilogue: C-row r of this lane's group = edge e0+lg*4+r
        int sn[4], dn[4];
#pragma unroll
        for (int r = 0; r < 4; ++r) {
            const int e = e0 + lg * 4 + r;
            sn[r] = ei[e];
            dn[r] = ei[NE + e];
        }

        // A fragments: edge row e0+ln, k = ks*32 + lg*8 + i ; split hi/lo bf16
        const float* ap = ea + (size_t)(e0 + ln) * 64 + lg * 8;
        float a0[8], a1[8];
        {
            const float4 v0 = *(const float4*)(ap);
            const float4 v1 = *(const float4*)(ap + 4);
            const float4 v2 = *(const float4*)(ap + 32);
            const float4 v3 = *(const float4*)(ap + 36);
            a0[0]=v0.x; a0[1]=v0.y; a0[2]=v0.z; a0[3]=v0.w;
            a0[4]=v1.x; a0[5]=v1.y; a0[6]=v1.z; a0[7]=v1.w;
            a1[0]=v2.x; a1[1]=v2.y; a1[2]=v2.z; a1[3]=v2.w;
            a1[4]=v3.x; a1[5]=v3.y; a1[6]=v3.z; a1[7]=v3.w;
        }
        short8v ah0, al0, ah1, al1;
#pragma unroll
        for (int i = 0; i < 8; ++i) {
            const short h0 = f2bf(a0[i]);
            ah0[i] = h0; al0[i] = f2bf(a0[i] - bf2f(h0));
            const short h1 = f2bf(a1[i]);
            ah1[i] = h1; al1[i] = f2bf(a1[i] - bf2f(h1));
        }

        f32x4 accf[8], accs[8];
        const f32x4 zz = {0.f, 0.f, 0.f, 0.f};
#pragma unroll
        for (int nt = 0; nt < 8; ++nt) { accf[nt] = zz; accs[nt] = zz; }

        const char* wb = (const char*)Wt;
#pragma unroll
        for (int nt = 0; nt < 8; ++nt) {
            const int rowf = nt * 16 + ln;
            const int rows = 128 + rowf;
            const short8v bf0 = *(const short8v*)(wb + rowf * 128 + ((lg * 16) ^ sw));
            const short8v bf1 = *(const short8v*)(wb + rowf * 128 + ((64 + lg * 16) ^ sw));
            const short8v bs0 = *(const short8v*)(wb + rows * 128 + ((lg * 16) ^ sw));
            const short8v bs1 = *(const short8v*)(wb + rows * 128 + ((64 + lg * 16) ^ sw));
            accf[nt] = __builtin_amdgcn_mfma_f32_16x16x32_bf16(ah0, bf0, accf[nt], 0, 0, 0);
            accf[nt] = __builtin_amdgcn_mfma_f32_16x16x32_bf16(al0, bf0, accf[nt], 0, 0, 0);
            accf[nt] = __builtin_amdgcn_mfma_f32_16x16x32_bf16(ah1, bf1, accf[nt], 0, 0, 0);
            accf[nt] = __builtin_amdgcn_mfma_f32_16x16x32_bf16(al1, bf1, accf[nt], 0, 0, 0);
            accs[nt] = __builtin_amdgcn_mfma_f32_16x16x32_bf16(ah0, bs0, accs[nt], 0, 0, 0);
            accs[nt] = __builtin_amdgcn_mfma_f32_16x16x32_bf16(al0, bs0, accs[nt], 0, 0, 0);
            accs[nt] = __builtin_amdgcn_mfma_f32_16x16x32_bf16(ah1, bs1, accs[nt], 0, 0, 0);
            accs[nt] = __builtin_amdgcn_mfma_f32_16x16x32_bf16(al1, bs1, accs[nt], 0, 0, 0);
        }

        // epilogue: gather interleaved tables, nonlinearity, scatter-add
#pragma unroll
        for (int r = 0; r < 4; ++r) {
            const float* td = Tdst + (size_t)dn[r] * 256 + 2 * ln;
            const float* ts = Tsrc + (size_t)sn[r] * 256 + 2 * ln;
            float* xo = xout + (size_t)dn[r] * 128 + ln;
#pragma unroll
            for (int nt = 0; nt < 8; ++nt) {
                const float2 gd = *(const float2*)(td + nt * 32);
                const float2 gs = *(const float2*)(ts + nt * 32);
                const float F = accf[nt][r] + gd.x + gs.x;
                const float S = accs[nt][r] + gd.y + gs.y;
                atomicAdd(xo + nt * 16, sigm(F) * sofp(S));
            }
        }
    }
}

// ---------------- batchnorm ----------------
__global__ __launch_bounds__(256) void k_bn_stats(const float* __restrict__ xv, float* __restrict__ stats)
{
    const int c = threadIdx.x & 127;
    const int half = threadIdx.x >> 7;
    float s = 0.0f, q = 0.0f;
    for (int r = blockIdx.x * 2 + half; r < NN; r += gridDim.x * 2) {
        const float v = xv[(size_t)r * 128 + c];
        s += v; q = fmaf(v, v, q);
    }
    __shared__ float sh[2][128];
    if (half) { sh[0][c] = s; sh[1][c] = q; }
    __syncthreads();
    if (!half) {
        s += sh[0][c]; q += sh[1][c];
        atomicAdd(&stats[c], s);
        atomicAdd(&stats[128 + c], q);
    }
}

__global__ void k_bn_finalize(const float* __restrict__ stats, const float* __restrict__ g,
                              const float* __restrict__ be, float* __restrict__ ab)
{
    const int c = threadIdx.x;
    const float mu = stats[c] * (1.0f / NN);
    const float var = stats[128 + c] * (1.0f / NN) - mu * mu;
    const float a = g[c] * rsqrtf(var + BN_EPS);
    ab[c] = a;
    ab[128 + c] = fmaf(-mu, a, be[c]);
}

__global__ __launch_bounds__(256) void k_bn_apply(float* __restrict__ xv, const float* __restrict__ ab)
{
    const size_t i = (size_t)blockIdx.x * 256 + threadIdx.x;
    const int c = ((int)i & 31) * 4;
    float4 v = ((float4*)xv)[i];
    v.x = fmaf(v.x, ab[c],     ab[128 + c]);
    v.y = fmaf(v.y, ab[c + 1], ab[128 + c + 1]);
    v.z = fmaf(v.z, ab[c + 2], ab[128 + c + 2]);
    v.w = fmaf(v.w, ab[c + 3], ab[128 + c + 3]);
    ((float4*)xv)[i] = v;
}

// ---------------- global mean pool ----------------
__global__ __launch_bounds__(256) void k_pool(const float* __restrict__ xv, const int* __restrict__ bat,
                                              float* __restrict__ pool, float* __restrict__ cnt)
{
    const int c = threadIdx.x & 127;
    const int half = threadIdx.x >> 7;
    for (int r = blockIdx.x * 2 + half; r < NN; r += gridDim.x * 2) {
        const int g = bat[r];
        atomicAdd(&pool[(size_t)g * 128 + c], xv[(size_t)r * 128 + c]);
        if (c == 0) atomicAdd(&cnt[g], 1.0f);
    }
}

__global__ __launch_bounds__(256) void k_pool_fin(const float* __restrict__ pool, const float* __restrict__ cnt,
                                                  float* __restrict__ out)
{
    const int i = blockIdx.x * 256 + threadIdx.x;
    out[i] = pool[i] / fmaxf(cnt[i >> 7], 1.0f);
}

extern "C" void kernel_launch(void* const* d_in, const int* in_sizes, int n_in,
                              void* d_out, int out_size, void* d_ws, size_t ws_size,
                              hipStream_t stream)
{
    const float* x   = (const float*)d_in[0];
    const int*   ei  = (const int*)d_in[1];
    const float* ea  = (const float*)d_in[2];
    const int*   bat = (const int*)d_in[3];
    const float* Wf[2] = { (const float*)d_in[4],  (const float*)d_in[10] };
    const float* bf[2] = { (const float*)d_in[5],  (const float*)d_in[11] };
    const float* Ws[2] = { (const float*)d_in[6],  (const float*)d_in[12] };
    const float* bs[2] = { (const float*)d_in[7],  (const float*)d_in[13] };
    const float* gm[2] = { (const float*)d_in[8],  (const float*)d_in[14] };
    const float* be[2] = { (const float*)d_in[9],  (const float*)d_in[15] };

    float* wsp = (float*)d_ws;
    float* Tdst = wsp;                               // [N][256] interleaved (f,s)
    float* Tsrc = Tdst + (size_t)NN * 256;           // [N][256]
    float* xb0  = Tsrc + (size_t)NN * 256;           // [N][128]
    float* xb1  = xb0 + (size_t)NN * 128;            // [N][128]
    float* stats = xb1 + (size_t)NN * 128;           // 256
    float* ab    = stats + 256;                      // 256
    float* pool  = ab + 256;                         // [G][128]
    float* cnt   = pool + (size_t)NG * 128;          // G
    float* xb[2] = { xb0, xb1 };

    hipMemsetAsync(pool, 0, ((size_t)NG * 128 + NG) * sizeof(float), stream);

    const float* xin = x;
    for (int l = 0; l < 2; ++l) {
        k_node_linear<<<dim3(782, 4), 256, 0, stream>>>(xin, Wf[l], Ws[l], bf[l], bs[l], Tdst, Tsrc);
        hipMemcpyAsync(xb[l], xin, (size_t)NN * 128 * sizeof(float), hipMemcpyDeviceToDevice, stream);
        k_edge2<<<1280, 256, 0, stream>>>(Tdst, Tsrc, Wf[l], Ws[l], ei, ea, xb[l]);
        hipMemsetAsync(stats, 0, 256 * sizeof(float), stream);
        k_bn_stats<<<256, 256, 0, stream>>>(xb[l], stats);
        k_bn_finalize<<<1, 128, 0, stream>>>(stats, gm[l], be[l], ab);
        k_bn_apply<<<6250, 256, 0, stream>>>(xb[l], ab);
        xin = xb[l];
    }
    k_pool<<<256, 256, 0, stream>>>(xb[1], bat, pool, cnt);
    k_pool_fin<<<NG * 128 / 256, 256, 0, stream>>>(pool, cnt, (float*)d_out);
}

// Round 3
// 1938.862 us; speedup vs baseline: 1.1009x; 1.1009x over previous
//
#include <hip/hip_runtime.h>

#define NN 50000
#define NE 800000
#define NG 256
#define BN_EPS 1e-5f
#define NNP (196 * 256)   // padded bins for scan

typedef __attribute__((ext_vector_type(8))) short short8v;
typedef __attribute__((ext_vector_type(4))) float f32x4;

__device__ __forceinline__ float sigm(float x) { return 1.0f / (1.0f + __expf(-x)); }
__device__ __forceinline__ float sofp(float x) { return fmaxf(x, 0.0f) + __logf(1.0f + __expf(-fabsf(x))); }

__device__ __forceinline__ short f2bf(float f) {
    union { float f; unsigned u; } a; a.f = f;
    unsigned r = a.u + 0x7FFFu + ((a.u >> 16) & 1u);
    return (short)(r >> 16);
}
__device__ __forceinline__ float bf2f(short h) {
    union { unsigned u; float f; } a; a.u = ((unsigned)(unsigned short)h) << 16;
    return a.f;
}

// ================= CSR build (counting sort by dst) =================
__global__ __launch_bounds__(256) void k_hist(const int* __restrict__ ei, int* __restrict__ hist)
{
    const int e = blockIdx.x * 256 + threadIdx.x;
    if (e < NE) atomicAdd(&hist[ei[NE + e]], 1);
}

__global__ __launch_bounds__(256) void k_scan_partial(const int* __restrict__ hist, int* __restrict__ partial)
{
    __shared__ int s[256];
    const int t = threadIdx.x;
    s[t] = hist[blockIdx.x * 256 + t];
    __syncthreads();
    for (int off = 1; off < 256; off <<= 1) {
        const int u = (t >= off) ? s[t - off] : 0;
        __syncthreads();
        s[t] += u;
        __syncthreads();
    }
    if (t == 255) partial[blockIdx.x] = s[255];
}

__global__ __launch_bounds__(256) void k_scan_top(const int* __restrict__ partial, int* __restrict__ topoff)
{
    __shared__ int s[256];
    const int t = threadIdx.x;
    const int v = (t < 196) ? partial[t] : 0;
    s[t] = v;
    __syncthreads();
    for (int off = 1; off < 256; off <<= 1) {
        const int u = (t >= off) ? s[t - off] : 0;
        __syncthreads();
        s[t] += u;
        __syncthreads();
    }
    if (t < 196) topoff[t] = s[t] - v;  // exclusive
}

__global__ __launch_bounds__(256) void k_scan_final(const int* __restrict__ hist, const int* __restrict__ topoff,
                                                    int* __restrict__ cursor)
{
    __shared__ int s[256];
    const int t = threadIdx.x;
    const int i = blockIdx.x * 256 + t;
    const int v = hist[i];
    s[t] = v;
    __syncthreads();
    for (int off = 1; off < 256; off <<= 1) {
        const int u = (t >= off) ? s[t - off] : 0;
        __syncthreads();
        s[t] += u;
        __syncthreads();
    }
    if (i < NN) cursor[i] = topoff[blockIdx.x] + s[t] - v;  // exclusive prefix
}

__global__ __launch_bounds__(256) void k_scatter(const int* __restrict__ ei, int* __restrict__ cursor,
                                                 int* __restrict__ seid, int* __restrict__ ssrc,
                                                 int* __restrict__ sdst)
{
    const int e = blockIdx.x * 256 + threadIdx.x;
    if (e < NE) {
        const int d = ei[NE + e];
        const int pos = atomicAdd(&cursor[d], 1);
        seid[pos] = e;
        ssrc[pos] = ei[e];
        sdst[pos] = d;
    }
}

// ================= node linear =================
// blockIdx.y = m: 0: Tdst f-part = x@Wf[0:128]   + bf
//                 1: Tsrc f-part = x@Wf[128:256]
//                 2: Tdst s-part = x@Ws[0:128]   + bs
//                 3: Tsrc s-part = x@Ws[128:256]
// Tables interleaved: T[n][2*c+0]=f-part, T[n][2*c+1]=s-part (256 f32/row)
__global__ __launch_bounds__(256) void k_node_linear(
    const float* __restrict__ x,
    const float* __restrict__ Wf, const float* __restrict__ Ws,
    const float* __restrict__ bf, const float* __restrict__ bs,
    float* __restrict__ Tdst, float* __restrict__ Tsrc)
{
    const int m = blockIdx.y;
    const int n0 = blockIdx.x * 64;
    const int tid = threadIdx.x;
    const int tx = tid & 15;
    const int ty = tid >> 4;
    const float* W = ((m & 2) ? Ws : Wf) + (size_t)(m & 1) * 128 * 128;

    __shared__ float As[16][64];
    __shared__ float Bs[16][128];

    float acc[4][8];
#pragma unroll
    for (int i = 0; i < 4; ++i)
#pragma unroll
        for (int j = 0; j < 8; ++j) acc[i][j] = 0.0f;

    const int lr = tid >> 2;
    const int lq = tid & 3;
    const int br = tid >> 5;
    const int bc = (tid & 31) * 4;

    for (int kc = 0; kc < 128; kc += 16) {
        float4 av = make_float4(0.f, 0.f, 0.f, 0.f);
        if (n0 + lr < NN) av = *(const float4*)(x + (size_t)(n0 + lr) * 128 + kc + lq * 4);
        const float4 b0 = *(const float4*)(W + (size_t)(kc + br) * 128 + bc);
        const float4 b1 = *(const float4*)(W + (size_t)(kc + br + 8) * 128 + bc);
        __syncthreads();
        As[lq * 4 + 0][lr] = av.x;
        As[lq * 4 + 1][lr] = av.y;
        As[lq * 4 + 2][lr] = av.z;
        As[lq * 4 + 3][lr] = av.w;
        *(float4*)&Bs[br][bc] = b0;
        *(float4*)&Bs[br + 8][bc] = b1;
        __syncthreads();
#pragma unroll
        for (int k = 0; k < 16; ++k) {
            float a[4], b[8];
#pragma unroll
            for (int i = 0; i < 4; ++i) a[i] = As[k][ty * 4 + i];
            const float4 q0 = *(const float4*)&Bs[k][tx * 8];
            const float4 q1 = *(const float4*)&Bs[k][tx * 8 + 4];
            b[0] = q0.x; b[1] = q0.y; b[2] = q0.z; b[3] = q0.w;
            b[4] = q1.x; b[5] = q1.y; b[6] = q1.z; b[7] = q1.w;
#pragma unroll
            for (int i = 0; i < 4; ++i)
#pragma unroll
                for (int j = 0; j < 8; ++j) acc[i][j] = fmaf(a[i], b[j], acc[i][j]);
        }
    }

    const float* bias = (m == 0) ? bf : ((m == 2) ? bs : nullptr);
    float bv[8];
#pragma unroll
    for (int j = 0; j < 8; ++j) bv[j] = bias ? bias[tx * 8 + j] : 0.0f;
    float* outb = ((m & 1) ? Tsrc : Tdst) + ((m >> 1) & 1);
#pragma unroll
    for (int i = 0; i < 4; ++i) {
        const int n = n0 + ty * 4 + i;
        if (n < NN) {
            float* p = outb + (size_t)n * 256 + tx * 16;
#pragma unroll
            for (int j = 0; j < 8; ++j) p[j * 2] = acc[i][j] + bv[j];
        }
    }
}

// ================= fused edge kernel (MFMA, dst-sorted) =================
__global__ __launch_bounds__(256, 4) void k_edge3(
    const float* __restrict__ Tdst, const float* __restrict__ Tsrc,
    const float* __restrict__ Wf, const float* __restrict__ Ws,
    const int* __restrict__ seid, const int* __restrict__ ssrc, const int* __restrict__ sdst,
    const float* __restrict__ ea, float* __restrict__ xout)
{
    __shared__ short Wt[256 * 64];  // [row=ch(0:128 f,128:256 s)][k], XOR-swizzled
    const int tid = threadIdx.x;
    for (int idx = tid; idx < 16384; idx += 256) {
        const int m = idx >> 13;
        const int kk = (idx >> 7) & 63;
        const int ch = idx & 127;
        const float w = (m ? Ws : Wf)[(size_t)(256 + kk) * 128 + ch];
        const int row = m * 128 + ch;
        const int bcol = (kk * 2) ^ ((row & 7) << 4);
        *(short*)((char*)Wt + row * 128 + bcol) = f2bf(w);
    }
    __syncthreads();

    const int lane = tid & 63;
    const int ln = lane & 15;
    const int lg = lane >> 4;
    const int gw = blockIdx.x * 4 + (tid >> 6);   // 0..4095
    const int sw = (ln & 7) << 4;

    const int NCH = NE / 16;                       // 50000 chunks
    const int lo = (int)(((long long)gw * NCH) >> 12);         // *NCH/4096
    const int hi = (int)(((long long)(gw + 1) * NCH) >> 12);

    for (int chk = lo; chk < hi; ++chk) {
        const int e0 = chk * 16;

        // this lane-group's 4 edges (rows lg*4+r of the C tile)
        int sn[4], dn[4];
#pragma unroll
        for (int r = 0; r < 4; ++r) {
            sn[r] = ssrc[e0 + lg * 4 + r];
            dn[r] = sdst[e0 + lg * 4 + r];
        }

        // A fragments: permuted edge row seid[e0+ln]
        const int eln = seid[e0 + ln];
        const float* ap = ea + (size_t)eln * 64 + lg * 8;
        float a0[8], a1[8];
        {
            const float4 v0 = *(const float4*)(ap);
            const float4 v1 = *(const float4*)(ap + 4);
            const float4 v2 = *(const float4*)(ap + 32);
            const float4 v3 = *(const float4*)(ap + 36);
            a0[0]=v0.x; a0[1]=v0.y; a0[2]=v0.z; a0[3]=v0.w;
            a0[4]=v1.x; a0[5]=v1.y; a0[6]=v1.z; a0[7]=v1.w;
            a1[0]=v2.x; a1[1]=v2.y; a1[2]=v2.z; a1[3]=v2.w;
            a1[4]=v3.x; a1[5]=v3.y; a1[6]=v3.z; a1[7]=v3.w;
        }
        short8v ah0, al0, ah1, al1;
#pragma unroll
        for (int i = 0; i < 8; ++i) {
            const short h0 = f2bf(a0[i]);
            ah0[i] = h0; al0[i] = f2bf(a0[i] - bf2f(h0));
            const short h1 = f2bf(a1[i]);
            ah1[i] = h1; al1[i] = f2bf(a1[i] - bf2f(h1));
        }

        f32x4 accf[8], accs[8];
        const f32x4 zz = {0.f, 0.f, 0.f, 0.f};
#pragma unroll
        for (int nt = 0; nt < 8; ++nt) { accf[nt] = zz; accs[nt] = zz; }

        const char* wb = (const char*)Wt;
#pragma unroll
        for (int nt = 0; nt < 8; ++nt) {
            const int rowf = nt * 16 + ln;
            const int rows = 128 + rowf;
            const short8v bf0 = *(const short8v*)(wb + rowf * 128 + ((lg * 16) ^ sw));
            const short8v bf1 = *(const short8v*)(wb + rowf * 128 + ((64 + lg * 16) ^ sw));
            const short8v bs0 = *(const short8v*)(wb + rows * 128 + ((lg * 16) ^ sw));
            const short8v bs1 = *(const short8v*)(wb + rows * 128 + ((64 + lg * 16) ^ sw));
            accf[nt] = __builtin_amdgcn_mfma_f32_16x16x32_bf16(ah0, bf0, accf[nt], 0, 0, 0);
            accf[nt] = __builtin_amdgcn_mfma_f32_16x16x32_bf16(al0, bf0, accf[nt], 0, 0, 0);
            accf[nt] = __builtin_amdgcn_mfma_f32_16x16x32_bf16(ah1, bf1, accf[nt], 0, 0, 0);
            accf[nt] = __builtin_amdgcn_mfma_f32_16x16x32_bf16(al1, bf1, accf[nt], 0, 0, 0);
            accs[nt] = __builtin_amdgcn_mfma_f32_16x16x32_bf16(ah0, bs0, accs[nt], 0, 0, 0);
            accs[nt] = __builtin_amdgcn_mfma_f32_16x16x32_bf16(al0, bs0, accs[nt], 0, 0, 0);
            accs[nt] = __builtin_amdgcn_mfma_f32_16x16x32_bf16(ah1, bs1, accs[nt], 0, 0, 0);
            accs[nt] = __builtin_amdgcn_mfma_f32_16x16x32_bf16(al1, bs1, accs[nt], 0, 0, 0);
        }

        // epilogue: dst-sorted — cache Tdst row & pre-reduce runs of equal dn
        float pend[8];
        float2 gdc[8];
        int pdn = dn[0];
        {
            const float* td = Tdst + (size_t)pdn * 256 + 2 * ln;
#pragma unroll
            for (int nt = 0; nt < 8; ++nt) { gdc[nt] = *(const float2*)(td + nt * 32); pend[nt] = 0.0f; }
        }
#pragma unroll
        for (int r = 0; r < 4; ++r) {
            if (dn[r] != pdn) {
                float* xo = xout + (size_t)pdn * 128 + ln;
#pragma unroll
                for (int nt = 0; nt < 8; ++nt) atomicAdd(xo + nt * 16, pend[nt]);
                pdn = dn[r];
                const float* td = Tdst + (size_t)pdn * 256 + 2 * ln;
#pragma unroll
                for (int nt = 0; nt < 8; ++nt) { gdc[nt] = *(const float2*)(td + nt * 32); pend[nt] = 0.0f; }
            }
            const float* ts = Tsrc + (size_t)sn[r] * 256 + 2 * ln;
#pragma unroll
            for (int nt = 0; nt < 8; ++nt) {
                const float2 gs = *(const float2*)(ts + nt * 32);
                const float F = accf[nt][r] + gdc[nt].x + gs.x;
                const float S = accs[nt][r] + gdc[nt].y + gs.y;
                pend[nt] += sigm(F) * sofp(S);
            }
        }
        {
            float* xo = xout + (size_t)pdn * 128 + ln;
#pragma unroll
            for (int nt = 0; nt < 8; ++nt) atomicAdd(xo + nt * 16, pend[nt]);
        }
    }
}

// ================= batchnorm =================
__global__ __launch_bounds__(256) void k_bn_stats(const float* __restrict__ xv, float* __restrict__ stats)
{
    const int c = threadIdx.x & 127;
    const int half = threadIdx.x >> 7;
    float s = 0.0f, q = 0.0f;
    for (int r = blockIdx.x * 2 + half; r < NN; r += gridDim.x * 2) {
        const float v = xv[(size_t)r * 128 + c];
        s += v; q = fmaf(v, v, q);
    }
    __shared__ float sh[2][128];
    if (half) { sh[0][c] = s; sh[1][c] = q; }
    __syncthreads();
    if (!half) {
        s += sh[0][c]; q += sh[1][c];
        atomicAdd(&stats[c], s);
        atomicAdd(&stats[128 + c], q);
    }
}

__global__ void k_bn_finalize(const float* __restrict__ stats, const float* __restrict__ g,
                              const float* __restrict__ be, float* __restrict__ ab)
{
    const int c = threadIdx.x;
    const float mu = stats[c] * (1.0f / NN);
    const float var = stats[128 + c] * (1.0f / NN) - mu * mu;
    const float a = g[c] * rsqrtf(var + BN_EPS);
    ab[c] = a;
    ab[128 + c] = fmaf(-mu, a, be[c]);
}

__global__ __launch_bounds__(256) void k_bn_apply(float* __restrict__ xv, const float* __restrict__ ab)
{
    const size_t i = (size_t)blockIdx.x * 256 + threadIdx.x;
    const int c = ((int)i & 31) * 4;
    float4 v = ((float4*)xv)[i];
    v.x = fmaf(v.x, ab[c],     ab[128 + c]);
    v.y = fmaf(v.y, ab[c + 1], ab[128 + c + 1]);
    v.z = fmaf(v.z, ab[c + 2], ab[128 + c + 2]);
    v.w = fmaf(v.w, ab[c + 3], ab[128 + c + 3]);
    ((float4*)xv)[i] = v;
}

// ================= global mean pool =================
__global__ __launch_bounds__(256) void k_pool(const float* __restrict__ xv, const int* __restrict__ bat,
                                              float* __restrict__ pool, float* __restrict__ cnt)
{
    const int c = threadIdx.x & 127;
    const int half = threadIdx.x >> 7;
    for (int r = blockIdx.x * 2 + half; r < NN; r += gridDim.x * 2) {
        const int g = bat[r];
        atomicAdd(&pool[(size_t)g * 128 + c], xv[(size_t)r * 128 + c]);
        if (c == 0) atomicAdd(&cnt[g], 1.0f);
    }
}

__global__ __launch_bounds__(256) void k_pool_fin(const float* __restrict__ pool, const float* __restrict__ cnt,
                                                  float* __restrict__ out)
{
    const int i = blockIdx.x * 256 + threadIdx.x;
    out[i] = pool[i] / fmaxf(cnt[i >> 7], 1.0f);
}

extern "C" void kernel_launch(void* const* d_in, const int* in_sizes, int n_in,
                              void* d_out, int out_size, void* d_ws, size_t ws_size,
                              hipStream_t stream)
{
    const float* x   = (const float*)d_in[0];
    const int*   ei  = (const int*)d_in[1];
    const float* ea  = (const float*)d_in[2];
    const int*   bat = (const int*)d_in[3];
    const float* Wf[2] = { (const float*)d_in[4],  (const float*)d_in[10] };
    const float* bf[2] = { (const float*)d_in[5],  (const float*)d_in[11] };
    const float* Ws[2] = { (const float*)d_in[6],  (const float*)d_in[12] };
    const float* bs[2] = { (const float*)d_in[7],  (const float*)d_in[13] };
    const float* gm[2] = { (const float*)d_in[8],  (const float*)d_in[14] };
    const float* be[2] = { (const float*)d_in[9],  (const float*)d_in[15] };

    float* wsp = (float*)d_ws;
    float* Tdst = wsp;                               // [N][256] interleaved (f,s)
    float* Tsrc = Tdst + (size_t)NN * 256;
    float* xb0  = Tsrc + (size_t)NN * 256;
    float* xb1  = xb0 + (size_t)NN * 128;
    float* stats = xb1 + (size_t)NN * 128;           // 256
    float* ab    = stats + 256;                      // 256
    float* pool  = ab + 256;                         // [G][128]
    float* cnt   = pool + (size_t)NG * 128;          // G
    int* hist    = (int*)(cnt + NG);                 // NNP
    int* partial = hist + NNP;                       // 256
    int* topoff  = partial + 256;                    // 256
    int* cursor  = topoff + 256;                     // NN
    int* seid    = cursor + NN;                      // NE
    int* ssrc    = seid + NE;                        // NE
    int* sdst    = ssrc + NE;                        // NE
    float* xb[2] = { xb0, xb1 };

    hipMemsetAsync(pool, 0, ((size_t)NG * 128 + NG) * sizeof(float), stream);
    hipMemsetAsync(hist, 0, NNP * sizeof(int), stream);

    // build dst-sorted edge permutation (once; reused by both layers)
    k_hist<<<(NE + 255) / 256, 256, 0, stream>>>(ei, hist);
    k_scan_partial<<<196, 256, 0, stream>>>(hist, partial);
    k_scan_top<<<1, 256, 0, stream>>>(partial, topoff);
    k_scan_final<<<196, 256, 0, stream>>>(hist, topoff, cursor);
    k_scatter<<<(NE + 255) / 256, 256, 0, stream>>>(ei, cursor, seid, ssrc, sdst);

    const float* xin = x;
    for (int l = 0; l < 2; ++l) {
        k_node_linear<<<dim3(782, 4), 256, 0, stream>>>(xin, Wf[l], Ws[l], bf[l], bs[l], Tdst, Tsrc);
        hipMemcpyAsync(xb[l], xin, (size_t)NN * 128 * sizeof(float), hipMemcpyDeviceToDevice, stream);
        k_edge3<<<1024, 256, 0, stream>>>(Tdst, Tsrc, Wf[l], Ws[l], seid, ssrc, sdst, ea, xb[l]);
        hipMemsetAsync(stats, 0, 256 * sizeof(float), stream);
        k_bn_stats<<<256, 256, 0, stream>>>(xb[l], stats);
        k_bn_finalize<<<1, 128, 0, stream>>>(stats, gm[l], be[l], ab);
        k_bn_apply<<<6250, 256, 0, stream>>>(xb[l], ab);
        xin = xb[l];
    }
    k_pool<<<256, 256, 0, stream>>>(xb[1], bat, pool, cnt);
    k_pool_fin<<<NG * 128 / 256, 256, 0, stream>>>(pool, cnt, (float*)d_out);
}

// Round 4
// 1770.618 us; speedup vs baseline: 1.2055x; 1.0950x over previous
//
#include <hip/hip_runtime.h>
#include <hip/hip_fp16.h>

#define NN 50000
#define NE 800000
#define NG 256
#define BN_EPS 1e-5f
#define NNP (196 * 256)   // padded bins for scan

typedef __attribute__((ext_vector_type(8))) short short8v;
typedef __attribute__((ext_vector_type(4))) float f32x4;

__device__ __forceinline__ float sigm(float x) { return 1.0f / (1.0f + __expf(-x)); }
__device__ __forceinline__ float sofp(float x) { return fmaxf(x, 0.0f) + __logf(1.0f + __expf(-fabsf(x))); }

__device__ __forceinline__ short f2bf(float f) {
    union { float f; unsigned u; } a; a.f = f;
    unsigned r = a.u + 0x7FFFu + ((a.u >> 16) & 1u);
    return (short)(r >> 16);
}
__device__ __forceinline__ float bf2f(short h) {
    union { unsigned u; float f; } a; a.u = ((unsigned)(unsigned short)h) << 16;
    return a.f;
}

// ================= CSR build (counting sort by dst) =================
__global__ __launch_bounds__(256) void k_hist(const int* __restrict__ ei, int* __restrict__ hist)
{
    const int e = blockIdx.x * 256 + threadIdx.x;
    if (e < NE) atomicAdd(&hist[ei[NE + e]], 1);
}

__global__ __launch_bounds__(256) void k_scan_partial(const int* __restrict__ hist, int* __restrict__ partial)
{
    __shared__ int s[256];
    const int t = threadIdx.x;
    s[t] = hist[blockIdx.x * 256 + t];
    __syncthreads();
    for (int off = 1; off < 256; off <<= 1) {
        const int u = (t >= off) ? s[t - off] : 0;
        __syncthreads();
        s[t] += u;
        __syncthreads();
    }
    if (t == 255) partial[blockIdx.x] = s[255];
}

__global__ __launch_bounds__(256) void k_scan_top(const int* __restrict__ partial, int* __restrict__ topoff)
{
    __shared__ int s[256];
    const int t = threadIdx.x;
    const int v = (t < 196) ? partial[t] : 0;
    s[t] = v;
    __syncthreads();
    for (int off = 1; off < 256; off <<= 1) {
        const int u = (t >= off) ? s[t - off] : 0;
        __syncthreads();
        s[t] += u;
        __syncthreads();
    }
    if (t < 196) topoff[t] = s[t] - v;  // exclusive
}

__global__ __launch_bounds__(256) void k_scan_final(const int* __restrict__ hist, const int* __restrict__ topoff,
                                                    int* __restrict__ cursor)
{
    __shared__ int s[256];
    const int t = threadIdx.x;
    const int i = blockIdx.x * 256 + t;
    const int v = hist[i];
    s[t] = v;
    __syncthreads();
    for (int off = 1; off < 256; off <<= 1) {
        const int u = (t >= off) ? s[t - off] : 0;
        __syncthreads();
        s[t] += u;
        __syncthreads();
    }
    if (i < NN) cursor[i] = topoff[blockIdx.x] + s[t] - v;  // exclusive prefix
}

__global__ __launch_bounds__(256) void k_scatter(const int* __restrict__ ei, int* __restrict__ cursor,
                                                 int* __restrict__ seid, int2* __restrict__ sds)
{
    const int e = blockIdx.x * 256 + threadIdx.x;
    if (e < NE) {
        const int d = ei[NE + e];
        const int pos = atomicAdd(&cursor[d], 1);
        seid[pos] = e;
        sds[pos] = make_int2(ei[e], d);
    }
}

// ================= node linear (MFMA, hi/lo x & hi/lo W) =================
// blockIdx.y = m: 0: Tdst f (bias bf)  1: Tsrc f  2: Tdst s (bias bs)  3: Tsrc s
// Tdst fp32 interleaved [n][2c+sel]; Tsrc packed fp16 pair per ch (ushort idx n*256+2c+sel)
__global__ __launch_bounds__(256) void k_nl(
    const float* __restrict__ xin,
    const float* __restrict__ Wf, const float* __restrict__ Ws,
    const float* __restrict__ bf, const float* __restrict__ bs,
    float* __restrict__ Tdst, unsigned short* __restrict__ Tsu)
{
    const int m = blockIdx.y;
    const int n0 = blockIdx.x * 64;
    const int tid = threadIdx.x;
    __shared__ short Wh[128 * 128];  // [ch][k] hi bf16, swizzled (32 KB)
    __shared__ short Wl[128 * 128];  // lo residual bf16 (32 KB)
    const float* W = ((m & 2) ? Ws : Wf) + (size_t)((m & 1) * 128) * 128;
    for (int idx = tid; idx < 16384; idx += 256) {
        const int k = idx >> 7, ch = idx & 127;
        const float w = W[(size_t)k * 128 + ch];
        const short h = f2bf(w);
        const short l = f2bf(w - bf2f(h));
        const int boff = ch * 256 + ((k * 2) ^ ((ch & 7) << 4));
        *(short*)((char*)Wh + boff) = h;
        *(short*)((char*)Wl + boff) = l;
    }
    __syncthreads();

    const int lane = tid & 63;
    const int ln = lane & 15;
    const int lg = lane >> 4;
    const int wv = tid >> 6;
    const int nb = n0 + wv * 16;
    const int sw = (ln & 7) << 4;

    f32x4 acc[8];
    const f32x4 zz = {0.f, 0.f, 0.f, 0.f};
#pragma unroll
    for (int nt = 0; nt < 8; ++nt) acc[nt] = zz;

    const char* wh = (const char*)Wh;
    const char* wl = (const char*)Wl;
    const int arow = (nb + ln < NN) ? (nb + ln) : (NN - 1);

    for (int kc = 0; kc < 4; ++kc) {
        const float* ap = xin + (size_t)arow * 128 + kc * 32 + lg * 8;
        const float4 u0 = *(const float4*)(ap);
        const float4 u1 = *(const float4*)(ap + 4);
        float av[8] = {u0.x, u0.y, u0.z, u0.w, u1.x, u1.y, u1.z, u1.w};
        short8v xh, xl;
#pragma unroll
        for (int i = 0; i < 8; ++i) {
            const short h = f2bf(av[i]);
            xh[i] = h; xl[i] = f2bf(av[i] - bf2f(h));
        }
        const int kofs = (kc * 64 + lg * 16) ^ sw;
#pragma unroll
        for (int nt = 0; nt < 8; ++nt) {
            const int row = nt * 16 + ln;
            const short8v bh = *(const short8v*)(wh + row * 256 + kofs);
            const short8v bl = *(const short8v*)(wl + row * 256 + kofs);
            acc[nt] = __builtin_amdgcn_mfma_f32_16x16x32_bf16(xh, bh, acc[nt], 0, 0, 0);
            acc[nt] = __builtin_amdgcn_mfma_f32_16x16x32_bf16(xl, bh, acc[nt], 0, 0, 0);
            acc[nt] = __builtin_amdgcn_mfma_f32_16x16x32_bf16(xh, bl, acc[nt], 0, 0, 0);
        }
    }

    const float* bias = (m == 0) ? bf : ((m == 2) ? bs : nullptr);
    const int sel = m >> 1;
    const bool isdst = (m & 1) == 0;
#pragma unroll
    for (int nt = 0; nt < 8; ++nt) {
        const int ch = nt * 16 + ln;
        const float bv = bias ? bias[ch] : 0.0f;
#pragma unroll
        for (int r = 0; r < 4; ++r) {
            const int node = nb + lg * 4 + r;
            if (node < NN) {
                const float v = acc[nt][r] + bv;
                if (isdst) Tdst[(size_t)node * 256 + 2 * ch + sel] = v;
                else       Tsu[(size_t)node * 256 + 2 * ch + sel] = __half_as_ushort(__float2half(v));
            }
        }
    }
}

// ================= fused edge kernel (MFMA, dst-sorted, pipelined) =================
__global__ __launch_bounds__(256, 3) void k_edge4(
    const float* __restrict__ Tdst, const __half2* __restrict__ Tsrch,
    const float* __restrict__ Wf, const float* __restrict__ Ws,
    const int* __restrict__ seid, const int2* __restrict__ sds,
    const float* __restrict__ ea, float* __restrict__ xout)
{
    __shared__ short Wt[256 * 64];  // [row=ch(0:128 f,128:256 s)][k], XOR-swizzled (32 KB)
    const int tid = threadIdx.x;
    for (int idx = tid; idx < 16384; idx += 256) {
        const int m = idx >> 13;
        const int kk = (idx >> 7) & 63;
        const int ch = idx & 127;
        const float w = (m ? Ws : Wf)[(size_t)(256 + kk) * 128 + ch];
        const int row = m * 128 + ch;
        const int bcol = (kk * 2) ^ ((row & 7) << 4);
        *(short*)((char*)Wt + row * 128 + bcol) = f2bf(w);
    }
    __syncthreads();

    const int lane = tid & 63;
    const int ln = lane & 15;
    const int lg = lane >> 4;
    const int gw = blockIdx.x * 4 + (tid >> 6);   // 0..3071 (768 blocks)
    const int nwv = gridDim.x * 4;
    const int sw = (ln & 7) << 4;

    const int NCH = NE / 16;
    const int lo = (int)(((long long)gw * NCH) / nwv);
    const int hi = (int)(((long long)(gw + 1) * NCH) / nwv);
    if (lo >= hi) return;

    // prefetched chunk state
    int sn[4], dn[4], eln;
    {
        const int e0 = lo * 16;
#pragma unroll
        for (int r = 0; r < 4; ++r) {
            const int2 p = sds[e0 + lg * 4 + r];
            sn[r] = p.x; dn[r] = p.y;
        }
        eln = seid[e0 + ln];
    }

    const char* wb = (const char*)Wt;

    for (int chk = lo; chk < hi; ++chk) {
        // 1. ea loads (address ready from prefetch)
        const float* ap = ea + (size_t)eln * 64 + lg * 8;
        const float4 v0 = *(const float4*)(ap);
        const float4 v1 = *(const float4*)(ap + 4);
        const float4 v2 = *(const float4*)(ap + 32);
        const float4 v3 = *(const float4*)(ap + 36);

        // 2. next-chunk index prefetch
        const int nchk = (chk + 1 < hi) ? (chk + 1) : chk;
        const int e0n = nchk * 16;
        int snn[4], dnn[4];
#pragma unroll
        for (int r = 0; r < 4; ++r) {
            const int2 p = sds[e0n + lg * 4 + r];
            snn[r] = p.x; dnn[r] = p.y;
        }
        const int elnn = seid[e0n + ln];

        // 3. Tsrc gathers issued before MFMA (latency hidden under compute)
        __half2 gsw[4][8];
#pragma unroll
        for (int r = 0; r < 4; ++r)
#pragma unroll
            for (int nt = 0; nt < 8; ++nt)
                gsw[r][nt] = Tsrch[(size_t)sn[r] * 128 + nt * 16 + ln];

        // 4. Tdst row for dn[0]
        float2 gdc[8];
        {
            const float* td = Tdst + (size_t)dn[0] * 256 + 2 * ln;
#pragma unroll
            for (int nt = 0; nt < 8; ++nt) gdc[nt] = *(const float2*)(td + nt * 32);
        }

        // 5. cvt + MFMA
        f32x4 accf[8], accs[8];
        const f32x4 zz = {0.f, 0.f, 0.f, 0.f};
#pragma unroll
        for (int nt = 0; nt < 8; ++nt) { accf[nt] = zz; accs[nt] = zz; }

        {
            float av[8] = {v0.x, v0.y, v0.z, v0.w, v1.x, v1.y, v1.z, v1.w};
            short8v ah, al;
#pragma unroll
            for (int i = 0; i < 8; ++i) {
                const short h = f2bf(av[i]);
                ah[i] = h; al[i] = f2bf(av[i] - bf2f(h));
            }
            const int kofs = (lg * 16) ^ sw;
#pragma unroll
            for (int nt = 0; nt < 8; ++nt) {
                const int rowf = nt * 16 + ln;
                const short8v bff = *(const short8v*)(wb + rowf * 128 + kofs);
                const short8v bss = *(const short8v*)(wb + (128 + rowf) * 128 + kofs);
                accf[nt] = __builtin_amdgcn_mfma_f32_16x16x32_bf16(ah, bff, accf[nt], 0, 0, 0);
                accf[nt] = __builtin_amdgcn_mfma_f32_16x16x32_bf16(al, bff, accf[nt], 0, 0, 0);
                accs[nt] = __builtin_amdgcn_mfma_f32_16x16x32_bf16(ah, bss, accs[nt], 0, 0, 0);
                accs[nt] = __builtin_amdgcn_mfma_f32_16x16x32_bf16(al, bss, accs[nt], 0, 0, 0);
            }
        }
        {
            float av[8] = {v2.x, v2.y, v2.z, v2.w, v3.x, v3.y, v3.z, v3.w};
            short8v ah, al;
#pragma unroll
            for (int i = 0; i < 8; ++i) {
                const short h = f2bf(av[i]);
                ah[i] = h; al[i] = f2bf(av[i] - bf2f(h));
            }
            const int kofs = (64 + lg * 16) ^ sw;
#pragma unroll
            for (int nt = 0; nt < 8; ++nt) {
                const int rowf = nt * 16 + ln;
                const short8v bff = *(const short8v*)(wb + rowf * 128 + kofs);
                const short8v bss = *(const short8v*)(wb + (128 + rowf) * 128 + kofs);
                accf[nt] = __builtin_amdgcn_mfma_f32_16x16x32_bf16(ah, bff, accf[nt], 0, 0, 0);
                accf[nt] = __builtin_amdgcn_mfma_f32_16x16x32_bf16(al, bff, accf[nt], 0, 0, 0);
                accs[nt] = __builtin_amdgcn_mfma_f32_16x16x32_bf16(ah, bss, accs[nt], 0, 0, 0);
                accs[nt] = __builtin_amdgcn_mfma_f32_16x16x32_bf16(al, bss, accs[nt], 0, 0, 0);
            }
        }

        // 6. epilogue: runs of equal dst pre-reduced in regs
        float pend[8];
#pragma unroll
        for (int nt = 0; nt < 8; ++nt) pend[nt] = 0.0f;
        int pdn = dn[0];
#pragma unroll
        for (int r = 0; r < 4; ++r) {
            if (dn[r] != pdn) {
                float* xo = xout + (size_t)pdn * 128 + ln;
#pragma unroll
                for (int nt = 0; nt < 8; ++nt) atomicAdd(xo + nt * 16, pend[nt]);
                pdn = dn[r];
                const float* td = Tdst + (size_t)pdn * 256 + 2 * ln;
#pragma unroll
                for (int nt = 0; nt < 8; ++nt) { gdc[nt] = *(const float2*)(td + nt * 32); pend[nt] = 0.0f; }
            }
#pragma unroll
            for (int nt = 0; nt < 8; ++nt) {
                const float2 gs = __half22float2(gsw[r][nt]);
                const float F = accf[nt][r] + gdc[nt].x + gs.x;
                const float S = accs[nt][r] + gdc[nt].y + gs.y;
                pend[nt] += sigm(F) * sofp(S);
            }
        }
        {
            float* xo = xout + (size_t)pdn * 128 + ln;
#pragma unroll
            for (int nt = 0; nt < 8; ++nt) atomicAdd(xo + nt * 16, pend[nt]);
        }

        // 7. rotate prefetch
#pragma unroll
        for (int r = 0; r < 4; ++r) { sn[r] = snn[r]; dn[r] = dnn[r]; }
        eln = elnn;
    }
}

// ================= batchnorm =================
__global__ __launch_bounds__(256) void k_bn_stats(const float* __restrict__ xv, float* __restrict__ stats)
{
    const int c = threadIdx.x & 127;
    const int half = threadIdx.x >> 7;
    float s = 0.0f, q = 0.0f;
    for (int r = blockIdx.x * 2 + half; r < NN; r += gridDim.x * 2) {
        const float v = xv[(size_t)r * 128 + c];
        s += v; q = fmaf(v, v, q);
    }
    __shared__ float sh[2][128];
    if (half) { sh[0][c] = s; sh[1][c] = q; }
    __syncthreads();
    if (!half) {
        s += sh[0][c]; q += sh[1][c];
        atomicAdd(&stats[c], s);
        atomicAdd(&stats[128 + c], q);
    }
}

__global__ void k_bn_finalize(const float* __restrict__ stats, const float* __restrict__ g,
                              const float* __restrict__ be, float* __restrict__ ab)
{
    const int c = threadIdx.x;
    const float mu = stats[c] * (1.0f / NN);
    const float var = stats[128 + c] * (1.0f / NN) - mu * mu;
    const float a = g[c] * rsqrtf(var + BN_EPS);
    ab[c] = a;
    ab[128 + c] = fmaf(-mu, a, be[c]);
}

// normalize src -> write dst
__global__ __launch_bounds__(256) void k_bn_apply_to(
    const float* __restrict__ xin, const float* __restrict__ ab, float* __restrict__ xo)
{
    const size_t i = (size_t)blockIdx.x * 256 + threadIdx.x;
    const int c = ((int)i & 31) * 4;
    float4 v = ((const float4*)xin)[i];
    v.x = fmaf(v.x, ab[c],     ab[128 + c]);
    v.y = fmaf(v.y, ab[c + 1], ab[128 + c + 1]);
    v.z = fmaf(v.z, ab[c + 2], ab[128 + c + 2]);
    v.w = fmaf(v.w, ab[c + 3], ab[128 + c + 3]);
    ((float4*)xo)[i] = v;
}

// normalize + pool in one pass (final layer)
__global__ __launch_bounds__(256) void k_bn_apply_pool(
    const float* __restrict__ xv, const float* __restrict__ ab, const int* __restrict__ bat,
    float* __restrict__ pool, float* __restrict__ cnt)
{
    const int c = threadIdx.x & 127;
    const int half = threadIdx.x >> 7;
    const float a = ab[c], b = ab[128 + c];
    for (int r = blockIdx.x * 2 + half; r < NN; r += gridDim.x * 2) {
        const int g = bat[r];
        atomicAdd(&pool[(size_t)g * 128 + c], fmaf(xv[(size_t)r * 128 + c], a, b));
        if (c == 0) atomicAdd(&cnt[g], 1.0f);
    }
}

__global__ __launch_bounds__(256) void k_pool_fin(const float* __restrict__ pool, const float* __restrict__ cnt,
                                                  float* __restrict__ out)
{
    const int i = blockIdx.x * 256 + threadIdx.x;
    out[i] = pool[i] / fmaxf(cnt[i >> 7], 1.0f);
}

extern "C" void kernel_launch(void* const* d_in, const int* in_sizes, int n_in,
                              void* d_out, int out_size, void* d_ws, size_t ws_size,
                              hipStream_t stream)
{
    const float* x   = (const float*)d_in[0];
    const int*   ei  = (const int*)d_in[1];
    const float* ea  = (const float*)d_in[2];
    const int*   bat = (const int*)d_in[3];
    const float* Wf[2] = { (const float*)d_in[4],  (const float*)d_in[10] };
    const float* bf[2] = { (const float*)d_in[5],  (const float*)d_in[11] };
    const float* Ws[2] = { (const float*)d_in[6],  (const float*)d_in[12] };
    const float* bs[2] = { (const float*)d_in[7],  (const float*)d_in[13] };
    const float* gm[2] = { (const float*)d_in[8],  (const float*)d_in[14] };
    const float* be[2] = { (const float*)d_in[9],  (const float*)d_in[15] };

    float* wsp = (float*)d_ws;
    float* Tdst = wsp;                               // [N][256] fp32 interleaved (f,s)
    float* Tsrcb = Tdst + (size_t)NN * 256;          // [N][128] packed half2 (f,s)
    float* xb0   = Tsrcb + (size_t)NN * 128;
    float* xb1   = xb0 + (size_t)NN * 128;
    float* stats0 = xb1 + (size_t)NN * 128;          // 256
    float* stats1 = stats0 + 256;                    // 256
    float* ab     = stats1 + 256;                    // 256
    float* pool   = ab + 256;                        // [G][128]
    float* cnt    = pool + (size_t)NG * 128;         // G
    int* hist    = (int*)(cnt + NG);                 // NNP
    int* partial = hist + NNP;                       // 256
    int* topoff  = partial + 256;                    // 256
    int* cursor  = topoff + 256;                     // NN
    int* seid    = cursor + NN;                      // NE
    int2* sds    = (int2*)(seid + NE);               // NE int2

    hipMemsetAsync(pool, 0, ((size_t)NG * 128 + NG) * sizeof(float), stream);
    hipMemsetAsync(hist, 0, NNP * sizeof(int), stream);
    hipMemsetAsync(stats0, 0, 512 * sizeof(float), stream);

    // build dst-sorted edge permutation (once; reused by both layers)
    k_hist<<<(NE + 255) / 256, 256, 0, stream>>>(ei, hist);
    k_scan_partial<<<196, 256, 0, stream>>>(hist, partial);
    k_scan_top<<<1, 256, 0, stream>>>(partial, topoff);
    k_scan_final<<<196, 256, 0, stream>>>(hist, topoff, cursor);
    k_scatter<<<(NE + 255) / 256, 256, 0, stream>>>(ei, cursor, seid, sds);

    // ---- layer 1 ----
    k_nl<<<dim3(782, 4), 256, 0, stream>>>(x, Wf[0], Ws[0], bf[0], bs[0], Tdst, (unsigned short*)Tsrcb);
    hipMemcpyAsync(xb0, x, (size_t)NN * 128 * sizeof(float), hipMemcpyDeviceToDevice, stream);
    k_edge4<<<768, 256, 0, stream>>>(Tdst, (const __half2*)Tsrcb, Wf[0], Ws[0], seid, sds, ea, xb0);
    k_bn_stats<<<256, 256, 0, stream>>>(xb0, stats0);
    k_bn_finalize<<<1, 128, 0, stream>>>(stats0, gm[0], be[0], ab);
    k_bn_apply_to<<<6250, 256, 0, stream>>>(xb0, ab, xb1);   // xb1 = BN(x + agg0)

    // ---- layer 2 ----
    k_nl<<<dim3(782, 4), 256, 0, stream>>>(xb1, Wf[1], Ws[1], bf[1], bs[1], Tdst, (unsigned short*)Tsrcb);
    k_edge4<<<768, 256, 0, stream>>>(Tdst, (const __half2*)Tsrcb, Wf[1], Ws[1], seid, sds, ea, xb1);
    k_bn_stats<<<256, 256, 0, stream>>>(xb1, stats1);
    k_bn_finalize<<<1, 128, 0, stream>>>(stats1, gm[1], be[1], ab);
    k_bn_apply_pool<<<256, 256, 0, stream>>>(xb1, ab, bat, pool, cnt);

    k_pool_fin<<<NG * 128 / 256, 256, 0, stream>>>(pool, cnt, (float*)d_out);
}

// Round 5
// 1519.251 us; speedup vs baseline: 1.4049x; 1.1655x over previous
//
#include <hip/hip_runtime.h>
#include <hip/hip_fp16.h>

#define NN 50000
#define NE 800000
#define NG 256
#define BN_EPS 1e-5f
#define NNP (196 * 256)   // padded bins for scan

typedef __attribute__((ext_vector_type(8))) _Float16 half8v;
typedef __attribute__((ext_vector_type(4))) float f32x4;

__device__ __forceinline__ float sigm(float x) { return 1.0f / (1.0f + __expf(-x)); }
__device__ __forceinline__ float sofp(float x) { return fmaxf(x, 0.0f) + __logf(1.0f + __expf(-fabsf(x))); }

// ================= CSR build (counting sort by dst) =================
__global__ __launch_bounds__(256) void k_hist(const int* __restrict__ ei, int* __restrict__ hist)
{
    const int e = blockIdx.x * 256 + threadIdx.x;
    if (e < NE) atomicAdd(&hist[ei[NE + e]], 1);
}

__global__ __launch_bounds__(256) void k_scan_partial(const int* __restrict__ hist, int* __restrict__ partial)
{
    __shared__ int s[256];
    const int t = threadIdx.x;
    s[t] = hist[blockIdx.x * 256 + t];
    __syncthreads();
    for (int off = 1; off < 256; off <<= 1) {
        const int u = (t >= off) ? s[t - off] : 0;
        __syncthreads();
        s[t] += u;
        __syncthreads();
    }
    if (t == 255) partial[blockIdx.x] = s[255];
}

__global__ __launch_bounds__(256) void k_scan_top(const int* __restrict__ partial, int* __restrict__ topoff)
{
    __shared__ int s[256];
    const int t = threadIdx.x;
    const int v = (t < 196) ? partial[t] : 0;
    s[t] = v;
    __syncthreads();
    for (int off = 1; off < 256; off <<= 1) {
        const int u = (t >= off) ? s[t - off] : 0;
        __syncthreads();
        s[t] += u;
        __syncthreads();
    }
    if (t < 196) topoff[t] = s[t] - v;  // exclusive
}

__global__ __launch_bounds__(256) void k_scan_final(const int* __restrict__ hist, const int* __restrict__ topoff,
                                                    int* __restrict__ cursor)
{
    __shared__ int s[256];
    const int t = threadIdx.x;
    const int i = blockIdx.x * 256 + t;
    const int v = hist[i];
    s[t] = v;
    __syncthreads();
    for (int off = 1; off < 256; off <<= 1) {
        const int u = (t >= off) ? s[t - off] : 0;
        __syncthreads();
        s[t] += u;
        __syncthreads();
    }
    if (i < NN) cursor[i] = topoff[blockIdx.x] + s[t] - v;  // exclusive prefix
}

__global__ __launch_bounds__(256) void k_scatter(const int* __restrict__ ei, int* __restrict__ cursor,
                                                 int* __restrict__ seid, int2* __restrict__ sds)
{
    const int e = blockIdx.x * 256 + threadIdx.x;
    if (e < NE) {
        const int d = ei[NE + e];
        const int pos = atomicAdd(&cursor[d], 1);
        seid[pos] = e;
        sds[pos] = make_int2(ei[e], d);
    }
}

// ================= one-time W conversion to fp16 pre-swizzled images =================
// Node images per (l,t): 32768 shorts: byte = g*32768 + ch*256 + ((k*2)^((ch&7)<<4))
// Edge images per l:     16384 shorts: byte = (g*128+ch)*128 + ((k*2)^(((g*128+ch)&7)<<4))
__global__ __launch_bounds__(256) void k_wcvt(
    const float* __restrict__ Wf0, const float* __restrict__ Ws0,
    const float* __restrict__ Wf1, const float* __restrict__ Ws1,
    unsigned short* __restrict__ Wn16, unsigned short* __restrict__ We16)
{
    const int i = blockIdx.x * 256 + threadIdx.x;
    if (i >= 2 * 81920) return;
    const int l = i / 81920;
    int r = i % 81920;
    const float* Wf = l ? Wf1 : Wf0;
    const float* Ws = l ? Ws1 : Ws0;
    if (r < 65536) {
        const int s = r >> 14;          // 0..3
        const int t = s & 1, g = s >> 1;
        const int j = r & 16383;
        const int k = j >> 7, ch = j & 127;
        const float v = (g ? Ws : Wf)[(size_t)(t * 128 + k) * 128 + ch];
        unsigned short* img = Wn16 + (size_t)(l * 2 + t) * 32768;
        const int boff = g * 32768 + ch * 256 + ((k * 2) ^ ((ch & 7) << 4));
        *(unsigned short*)((char*)img + boff) = __half_as_ushort(__float2half(v));
    } else {
        r -= 65536;
        const int g = r >> 13;
        const int j = r & 8191;
        const int k = j >> 7, ch = j & 127;
        const float v = (g ? Ws : Wf)[(size_t)(256 + k) * 128 + ch];
        const int row = g * 128 + ch;
        unsigned short* img = We16 + (size_t)l * 16384;
        const int boff = row * 128 + ((k * 2) ^ ((row & 7) << 4));
        *(unsigned short*)((char*)img + boff) = __half_as_ushort(__float2half(v));
    }
}

// ================= node linear (MFMA f16, x hi/lo) =================
// blockIdx.y = t: 0 -> Tdst (fp32 interleaved, +bias), 1 -> Tsrc (packed half2)
__global__ __launch_bounds__(256) void k_nl(
    const float* __restrict__ xin, const unsigned short* __restrict__ Wimg,
    const float* __restrict__ bf, const float* __restrict__ bs,
    float* __restrict__ Tdst, unsigned int* __restrict__ Tsu)
{
    const int t = blockIdx.y;
    __shared__ short Wg[32768];   // 64 KB: gate f at 0, gate s at +32768 B
    const int tid = threadIdx.x;
    {
        const int4* src = (const int4*)(Wimg + (size_t)t * 32768);
        int4* dst = (int4*)Wg;
        for (int j = tid; j < 4096; j += 256) dst[j] = src[j];
    }
    __syncthreads();

    const int lane = tid & 63;
    const int ln = lane & 15, lg = lane >> 4, wv = tid >> 6;
    const int nb = blockIdx.x * 64 + wv * 16;
    const int arow = (nb + ln < NN) ? nb + ln : NN - 1;
    const int sw = (ln & 7) << 4;

    f32x4 accF[8], accS[8];
    const f32x4 zz = {0.f, 0.f, 0.f, 0.f};
#pragma unroll
    for (int nt = 0; nt < 8; ++nt) { accF[nt] = zz; accS[nt] = zz; }

    const char* wg = (const char*)Wg;
    for (int kc = 0; kc < 4; ++kc) {
        const float* ap = xin + (size_t)arow * 128 + kc * 32 + lg * 8;
        const float4 u0 = *(const float4*)(ap);
        const float4 u1 = *(const float4*)(ap + 4);
        const float av[8] = {u0.x, u0.y, u0.z, u0.w, u1.x, u1.y, u1.z, u1.w};
        half8v xh, xl;
#pragma unroll
        for (int i = 0; i < 8; ++i) {
            const _Float16 h = (_Float16)av[i];
            xh[i] = h;
            xl[i] = (_Float16)(av[i] - (float)h);
        }
        const int kofs = (kc * 64 + lg * 16) ^ sw;
#pragma unroll
        for (int nt = 0; nt < 8; ++nt) {
            const int row = nt * 16 + ln;
            const half8v bF = *(const half8v*)(wg + row * 256 + kofs);
            const half8v bS = *(const half8v*)(wg + 32768 + row * 256 + kofs);
            accF[nt] = __builtin_amdgcn_mfma_f32_16x16x32_f16(xh, bF, accF[nt], 0, 0, 0);
            accF[nt] = __builtin_amdgcn_mfma_f32_16x16x32_f16(xl, bF, accF[nt], 0, 0, 0);
            accS[nt] = __builtin_amdgcn_mfma_f32_16x16x32_f16(xh, bS, accS[nt], 0, 0, 0);
            accS[nt] = __builtin_amdgcn_mfma_f32_16x16x32_f16(xl, bS, accS[nt], 0, 0, 0);
        }
    }

#pragma unroll
    for (int nt = 0; nt < 8; ++nt) {
        const int ch = nt * 16 + ln;
        float addF = 0.f, addS = 0.f;
        if (t == 0) { addF = bf[ch]; addS = bs[ch]; }
#pragma unroll
        for (int r = 0; r < 4; ++r) {
            const int node = nb + lg * 4 + r;
            if (node < NN) {
                const float F = accF[nt][r] + addF;
                const float S = accS[nt][r] + addS;
                if (t == 0) {
                    *(float2*)(Tdst + (size_t)node * 256 + 2 * ch) = make_float2(F, S);
                } else {
                    const __half2 p = __floats2half2_rn(F, S);
                    Tsu[(size_t)node * 128 + ch] = *(const unsigned int*)&p;
                }
            }
        }
    }
}

// ================= fused edge kernel (MFMA f16, contiguous per-group ranges, carry) =================
__global__ __launch_bounds__(256, 4) void k_edge5(
    const float* __restrict__ Tdst, const unsigned int* __restrict__ Tsrcw,
    const unsigned short* __restrict__ Wimg,
    const int* __restrict__ seid, const int2* __restrict__ sds,
    const float* __restrict__ ea, float* __restrict__ xout)
{
    __shared__ short Wt[16384];   // 32 KB edge-slice image
    const int tid = threadIdx.x;
    {
        const int4* src = (const int4*)Wimg;
        int4* dst = (int4*)Wt;
        for (int j = tid; j < 2048; j += 256) dst[j] = src[j];
    }
    __syncthreads();

    const int lane = tid & 63;
    const int ln = lane & 15, lg = lane >> 4;
    const int gw = blockIdx.x * 4 + (tid >> 6);
    const int nwv = gridDim.x * 4;
    const int sw = (ln & 7) << 4;

    const int NCH = NE / 16;
    const int lo = (int)(((long long)gw * NCH) / nwv);
    const int hi = (int)(((long long)(gw + 1) * NCH) / nwv);
    if (lo >= hi) return;
    const int wlo = lo * 16;
    const int Q = (hi - lo) * 4;       // edges per lane-group (contiguous, multiple of 4)
    const int NT = hi - lo;

    const int abase = wlo + (ln >> 2) * Q + (ln & 3);  // A-row edge (+ t*4)
    const int gbase = wlo + lg * Q;                    // C-group edge base (+ t*4 + r)

    float pend[8];
    float2 gdc[8];
    int pdn = -1;
#pragma unroll
    for (int nt = 0; nt < 8; ++nt) { pend[nt] = 0.f; gdc[nt] = make_float2(0.f, 0.f); }

    const char* wb = (const char*)Wt;

    for (int t = 0; t < NT; ++t) {
        // per-group indices (contiguous within group's sub-range)
        const int e4 = gbase + t * 4;
        const int4 p01 = *(const int4*)(sds + e4);
        const int4 p23 = *(const int4*)(sds + e4 + 2);
        const int sn[4] = {p01.x, p01.z, p23.x, p23.z};
        const int dn[4] = {p01.y, p01.w, p23.y, p23.w};
        const int eln = seid[abase + t * 4];

        // ea row fp32 -> fp16 frags
        const float* ap = ea + (size_t)eln * 64 + lg * 8;
        const float4 v0 = *(const float4*)(ap);
        const float4 v1 = *(const float4*)(ap + 4);
        const float4 v2 = *(const float4*)(ap + 32);
        const float4 v3 = *(const float4*)(ap + 36);

        // Tsrc gathers (issued before MFMA)
        unsigned int gsw[4][8];
#pragma unroll
        for (int r = 0; r < 4; ++r)
#pragma unroll
            for (int nt = 0; nt < 8; ++nt)
                gsw[r][nt] = Tsrcw[(size_t)sn[r] * 128 + nt * 16 + ln];

        half8v a0, a1;
        {
            const float av[8] = {v0.x, v0.y, v0.z, v0.w, v1.x, v1.y, v1.z, v1.w};
#pragma unroll
            for (int i = 0; i < 8; ++i) a0[i] = (_Float16)av[i];
        }
        {
            const float av[8] = {v2.x, v2.y, v2.z, v2.w, v3.x, v3.y, v3.z, v3.w};
#pragma unroll
            for (int i = 0; i < 8; ++i) a1[i] = (_Float16)av[i];
        }

        f32x4 accf[8], accs[8];
        const f32x4 zz = {0.f, 0.f, 0.f, 0.f};
#pragma unroll
        for (int nt = 0; nt < 8; ++nt) { accf[nt] = zz; accs[nt] = zz; }

#pragma unroll
        for (int nt = 0; nt < 8; ++nt) {
            const int rowf = nt * 16 + ln;
            const half8v bf0 = *(const half8v*)(wb + rowf * 128 + ((lg * 16) ^ sw));
            const half8v bf1 = *(const half8v*)(wb + rowf * 128 + ((64 + lg * 16) ^ sw));
            const half8v bs0 = *(const half8v*)(wb + (128 + rowf) * 128 + ((lg * 16) ^ sw));
            const half8v bs1 = *(const half8v*)(wb + (128 + rowf) * 128 + ((64 + lg * 16) ^ sw));
            accf[nt] = __builtin_amdgcn_mfma_f32_16x16x32_f16(a0, bf0, accf[nt], 0, 0, 0);
            accf[nt] = __builtin_amdgcn_mfma_f32_16x16x32_f16(a1, bf1, accf[nt], 0, 0, 0);
            accs[nt] = __builtin_amdgcn_mfma_f32_16x16x32_f16(a0, bs0, accs[nt], 0, 0, 0);
            accs[nt] = __builtin_amdgcn_mfma_f32_16x16x32_f16(a1, bs1, accs[nt], 0, 0, 0);
        }

        // epilogue: runs carried across tiles (flush only on dst change)
#pragma unroll
        for (int r = 0; r < 4; ++r) {
            if (dn[r] != pdn) {
                if (pdn >= 0) {
                    float* xo = xout + (size_t)pdn * 128 + ln;
#pragma unroll
                    for (int nt = 0; nt < 8; ++nt) atomicAdd(xo + nt * 16, pend[nt]);
                }
                pdn = dn[r];
                const float* td = Tdst + (size_t)pdn * 256 + 2 * ln;
#pragma unroll
                for (int nt = 0; nt < 8; ++nt) { gdc[nt] = *(const float2*)(td + nt * 32); pend[nt] = 0.f; }
            }
#pragma unroll
            for (int nt = 0; nt < 8; ++nt) {
                const __half2 hw = *(const __half2*)&gsw[r][nt];
                const float2 gs = __half22float2(hw);
                const float F = accf[nt][r] + gdc[nt].x + gs.x;
                const float S = accs[nt][r] + gdc[nt].y + gs.y;
                pend[nt] += sigm(F) * sofp(S);
            }
        }
    }
    if (pdn >= 0) {
        float* xo = xout + (size_t)pdn * 128 + ln;
#pragma unroll
        for (int nt = 0; nt < 8; ++nt) atomicAdd(xo + nt * 16, pend[nt]);
    }
}

// ================= batchnorm =================
__global__ __launch_bounds__(256) void k_bn_stats(const float* __restrict__ xv, float* __restrict__ stats)
{
    const int c = threadIdx.x & 127;
    const int half = threadIdx.x >> 7;
    float s = 0.0f, q = 0.0f;
    for (int r = blockIdx.x * 2 + half; r < NN; r += gridDim.x * 2) {
        const float v = xv[(size_t)r * 128 + c];
        s += v; q = fmaf(v, v, q);
    }
    __shared__ float sh[2][128];
    if (half) { sh[0][c] = s; sh[1][c] = q; }
    __syncthreads();
    if (!half) {
        s += sh[0][c]; q += sh[1][c];
        atomicAdd(&stats[c], s);
        atomicAdd(&stats[128 + c], q);
    }
}

__global__ void k_bn_finalize(const float* __restrict__ stats, const float* __restrict__ g,
                              const float* __restrict__ be, float* __restrict__ ab)
{
    const int c = threadIdx.x;
    const float mu = stats[c] * (1.0f / NN);
    const float var = stats[128 + c] * (1.0f / NN) - mu * mu;
    const float a = g[c] * rsqrtf(var + BN_EPS);
    ab[c] = a;
    ab[128 + c] = fmaf(-mu, a, be[c]);
}

__global__ __launch_bounds__(256) void k_bn_apply_to(
    const float* __restrict__ xin, const float* __restrict__ ab, float* __restrict__ xo)
{
    const size_t i = (size_t)blockIdx.x * 256 + threadIdx.x;
    const int c = ((int)i & 31) * 4;
    float4 v = ((const float4*)xin)[i];
    v.x = fmaf(v.x, ab[c],     ab[128 + c]);
    v.y = fmaf(v.y, ab[c + 1], ab[128 + c + 1]);
    v.z = fmaf(v.z, ab[c + 2], ab[128 + c + 2]);
    v.w = fmaf(v.w, ab[c + 3], ab[128 + c + 3]);
    ((float4*)xo)[i] = v;
}

__global__ __launch_bounds__(256) void k_bn_apply_pool(
    const float* __restrict__ xv, const float* __restrict__ ab, const int* __restrict__ bat,
    float* __restrict__ pool, float* __restrict__ cnt)
{
    const int c = threadIdx.x & 127;
    const int half = threadIdx.x >> 7;
    const float a = ab[c], b = ab[128 + c];
    for (int r = blockIdx.x * 2 + half; r < NN; r += gridDim.x * 2) {
        const int g = bat[r];
        atomicAdd(&pool[(size_t)g * 128 + c], fmaf(xv[(size_t)r * 128 + c], a, b));
        if (c == 0) atomicAdd(&cnt[g], 1.0f);
    }
}

__global__ __launch_bounds__(256) void k_pool_fin(const float* __restrict__ pool, const float* __restrict__ cnt,
                                                  float* __restrict__ out)
{
    const int i = blockIdx.x * 256 + threadIdx.x;
    out[i] = pool[i] / fmaxf(cnt[i >> 7], 1.0f);
}

extern "C" void kernel_launch(void* const* d_in, const int* in_sizes, int n_in,
                              void* d_out, int out_size, void* d_ws, size_t ws_size,
                              hipStream_t stream)
{
    const float* x   = (const float*)d_in[0];
    const int*   ei  = (const int*)d_in[1];
    const float* ea  = (const float*)d_in[2];
    const int*   bat = (const int*)d_in[3];
    const float* Wf[2] = { (const float*)d_in[4],  (const float*)d_in[10] };
    const float* bf[2] = { (const float*)d_in[5],  (const float*)d_in[11] };
    const float* Ws[2] = { (const float*)d_in[6],  (const float*)d_in[12] };
    const float* bs[2] = { (const float*)d_in[7],  (const float*)d_in[13] };
    const float* gm[2] = { (const float*)d_in[8],  (const float*)d_in[14] };
    const float* be[2] = { (const float*)d_in[9],  (const float*)d_in[15] };

    float* wsp = (float*)d_ws;
    float* Tdst = wsp;                               // [N][256] fp32 interleaved (f,s)
    float* Tsrcb = Tdst + (size_t)NN * 256;          // [N][128] packed half2 (f,s)
    float* xb0   = Tsrcb + (size_t)NN * 128;
    float* xb1   = xb0 + (size_t)NN * 128;
    float* stats0 = xb1 + (size_t)NN * 128;          // 256
    float* stats1 = stats0 + 256;                    // 256
    float* ab     = stats1 + 256;                    // 256
    float* pool   = ab + 256;                        // [G][128]
    float* cnt    = pool + (size_t)NG * 128;         // G
    int* hist    = (int*)(cnt + NG);                 // NNP
    int* partial = hist + NNP;                       // 256
    int* topoff  = partial + 256;                    // 256
    int* cursor  = topoff + 256;                     // NN
    int* seid    = cursor + NN;                      // NE
    int2* sds    = (int2*)(seid + NE);               // NE int2
    unsigned short* Wn16 = (unsigned short*)(sds + NE);  // 131072 ushorts (256 KB)
    unsigned short* We16 = Wn16 + 131072;                // 32768 ushorts (64 KB)

    hipMemsetAsync(pool, 0, ((size_t)NG * 128 + NG) * sizeof(float), stream);
    hipMemsetAsync(hist, 0, NNP * sizeof(int), stream);
    hipMemsetAsync(stats0, 0, 512 * sizeof(float), stream);

    // one-time: W conversion + dst-sorted edge permutation
    k_wcvt<<<640, 256, 0, stream>>>(Wf[0], Ws[0], Wf[1], Ws[1], Wn16, We16);
    k_hist<<<(NE + 255) / 256, 256, 0, stream>>>(ei, hist);
    k_scan_partial<<<196, 256, 0, stream>>>(hist, partial);
    k_scan_top<<<1, 256, 0, stream>>>(partial, topoff);
    k_scan_final<<<196, 256, 0, stream>>>(hist, topoff, cursor);
    k_scatter<<<(NE + 255) / 256, 256, 0, stream>>>(ei, cursor, seid, sds);

    // ---- layer 1 ----
    k_nl<<<dim3(782, 2), 256, 0, stream>>>(x, Wn16, bf[0], bs[0], Tdst, (unsigned int*)Tsrcb);
    hipMemcpyAsync(xb0, x, (size_t)NN * 128 * sizeof(float), hipMemcpyDeviceToDevice, stream);
    k_edge5<<<768, 256, 0, stream>>>(Tdst, (const unsigned int*)Tsrcb, We16, seid, sds, ea, xb0);
    k_bn_stats<<<256, 256, 0, stream>>>(xb0, stats0);
    k_bn_finalize<<<1, 128, 0, stream>>>(stats0, gm[0], be[0], ab);
    k_bn_apply_to<<<6250, 256, 0, stream>>>(xb0, ab, xb1);   // xb1 = BN(x + agg0)

    // ---- layer 2 ----
    k_nl<<<dim3(782, 2), 256, 0, stream>>>(xb1, Wn16 + 65536, bf[1], bs[1], Tdst, (unsigned int*)Tsrcb);
    k_edge5<<<768, 256, 0, stream>>>(Tdst, (const unsigned int*)Tsrcb, We16 + 16384, seid, sds, ea, xb1);
    k_bn_stats<<<256, 256, 0, stream>>>(xb1, stats1);
    k_bn_finalize<<<1, 128, 0, stream>>>(stats1, gm[1], be[1], ab);
    k_bn_apply_pool<<<256, 256, 0, stream>>>(xb1, ab, bat, pool, cnt);

    k_pool_fin<<<NG * 128 / 256, 256, 0, stream>>>(pool, cnt, (float*)d_out);
}

// Round 6
// 1366.315 us; speedup vs baseline: 1.5622x; 1.1119x over previous
//
#include <hip/hip_runtime.h>
#include <hip/hip_fp16.h>

#define NN 50000
#define NE 800000
#define NG 256
#define BN_EPS 1e-5f
#define NNP (196 * 256)   // padded bins for scan

typedef __attribute__((ext_vector_type(8))) _Float16 half8v;
typedef __attribute__((ext_vector_type(4))) _Float16 half4v;
typedef __attribute__((ext_vector_type(4))) float f32x4;

__device__ __forceinline__ float sigm(float x) { return 1.0f / (1.0f + __expf(-x)); }
__device__ __forceinline__ float sofp(float x) { return fmaxf(x, 0.0f) + __logf(1.0f + __expf(-fabsf(x))); }

// ================= CSR build (counting sort by dst) =================
__global__ __launch_bounds__(256) void k_hist(const int* __restrict__ ei, int* __restrict__ hist)
{
    const int e = blockIdx.x * 256 + threadIdx.x;
    if (e < NE) atomicAdd(&hist[ei[NE + e]], 1);
}

__global__ __launch_bounds__(256) void k_scan_partial(const int* __restrict__ hist, int* __restrict__ partial)
{
    __shared__ int s[256];
    const int t = threadIdx.x;
    s[t] = hist[blockIdx.x * 256 + t];
    __syncthreads();
    for (int off = 1; off < 256; off <<= 1) {
        const int u = (t >= off) ? s[t - off] : 0;
        __syncthreads();
        s[t] += u;
        __syncthreads();
    }
    if (t == 255) partial[blockIdx.x] = s[255];
}

__global__ __launch_bounds__(256) void k_scan_top(const int* __restrict__ partial, int* __restrict__ topoff)
{
    __shared__ int s[256];
    const int t = threadIdx.x;
    const int v = (t < 196) ? partial[t] : 0;
    s[t] = v;
    __syncthreads();
    for (int off = 1; off < 256; off <<= 1) {
        const int u = (t >= off) ? s[t - off] : 0;
        __syncthreads();
        s[t] += u;
        __syncthreads();
    }
    if (t < 196) topoff[t] = s[t] - v;  // exclusive
}

__global__ __launch_bounds__(256) void k_scan_final(const int* __restrict__ hist, const int* __restrict__ topoff,
                                                    int* __restrict__ cursor)
{
    __shared__ int s[256];
    const int t = threadIdx.x;
    const int i = blockIdx.x * 256 + t;
    const int v = hist[i];
    s[t] = v;
    __syncthreads();
    for (int off = 1; off < 256; off <<= 1) {
        const int u = (t >= off) ? s[t - off] : 0;
        __syncthreads();
        s[t] += u;
        __syncthreads();
    }
    if (i < NN) cursor[i] = topoff[blockIdx.x] + s[t] - v;  // exclusive prefix
}

__global__ __launch_bounds__(256) void k_scatter(const int* __restrict__ ei, int* __restrict__ cursor,
                                                 int* __restrict__ seid, int2* __restrict__ sds)
{
    const int e = blockIdx.x * 256 + threadIdx.x;
    if (e < NE) {
        const int d = ei[NE + e];
        const int pos = atomicAdd(&cursor[d], 1);
        seid[pos] = e;
        sds[pos] = make_int2(ei[e], d);
    }
}

// permute edge_attr into sorted order, fp16 (one-time)
__global__ __launch_bounds__(256) void k_eperm(const int* __restrict__ seid, const float* __restrict__ ea,
                                               _Float16* __restrict__ eas)
{
    const int r = blockIdx.x * 16 + (threadIdx.x >> 4);
    const int j = threadIdx.x & 15;
    const int e = seid[r];
    const float4 v = *(const float4*)(ea + (size_t)e * 64 + j * 4);
    half4v h;
    h[0] = (_Float16)v.x; h[1] = (_Float16)v.y; h[2] = (_Float16)v.z; h[3] = (_Float16)v.w;
    *(half4v*)(eas + (size_t)r * 64 + j * 4) = h;
}

// ================= one-time W conversion to fp16 pre-swizzled images =================
__global__ __launch_bounds__(256) void k_wcvt(
    const float* __restrict__ Wf0, const float* __restrict__ Ws0,
    const float* __restrict__ Wf1, const float* __restrict__ Ws1,
    unsigned short* __restrict__ Wn16, unsigned short* __restrict__ We16)
{
    const int i = blockIdx.x * 256 + threadIdx.x;
    if (i >= 2 * 81920) return;
    const int l = i / 81920;
    int r = i % 81920;
    const float* Wf = l ? Wf1 : Wf0;
    const float* Ws = l ? Ws1 : Ws0;
    if (r < 65536) {
        const int s = r >> 14;          // 0..3
        const int t = s & 1, g = s >> 1;
        const int j = r & 16383;
        const int k = j >> 7, ch = j & 127;
        const float v = (g ? Ws : Wf)[(size_t)(t * 128 + k) * 128 + ch];
        unsigned short* img = Wn16 + (size_t)(l * 2 + t) * 32768;
        const int boff = g * 32768 + ch * 256 + ((k * 2) ^ ((ch & 7) << 4));
        *(unsigned short*)((char*)img + boff) = __half_as_ushort(__float2half(v));
    } else {
        r -= 65536;
        const int g = r >> 13;
        const int j = r & 8191;
        const int k = j >> 7, ch = j & 127;
        const float v = (g ? Ws : Wf)[(size_t)(256 + k) * 128 + ch];
        const int row = g * 128 + ch;
        unsigned short* img = We16 + (size_t)l * 16384;
        const int boff = row * 128 + ((k * 2) ^ ((row & 7) << 4));
        *(unsigned short*)((char*)img + boff) = __half_as_ushort(__float2half(v));
    }
}

// ================= node linear (MFMA f16, x hi/lo, packed fp16 tables) =================
// blockIdx.y = t: 0 -> Tdw (+bias), 1 -> Tsw. Both packed half2 (f,s) per channel.
__global__ __launch_bounds__(256) void k_nl(
    const float* __restrict__ xin, const unsigned short* __restrict__ Wimg,
    const float* __restrict__ bfv, const float* __restrict__ bsv,
    unsigned int* __restrict__ Tdw, unsigned int* __restrict__ Tsw)
{
    const int t = blockIdx.y;
    __shared__ short Wg[32768];   // 64 KB: gate f at 0, gate s at +32768 B
    const int tid = threadIdx.x;
    {
        const int4* src = (const int4*)(Wimg + (size_t)t * 32768);
        int4* dst = (int4*)Wg;
        for (int j = tid; j < 4096; j += 256) dst[j] = src[j];
    }
    __syncthreads();

    const int lane = tid & 63;
    const int ln = lane & 15, lg = lane >> 4, wv = tid >> 6;
    const int nb = blockIdx.x * 64 + wv * 16;
    const int arow = (nb + ln < NN) ? nb + ln : NN - 1;
    const int sw = (ln & 7) << 4;

    f32x4 accF[8], accS[8];
    const f32x4 zz = {0.f, 0.f, 0.f, 0.f};
#pragma unroll
    for (int nt = 0; nt < 8; ++nt) { accF[nt] = zz; accS[nt] = zz; }

    const char* wg = (const char*)Wg;
    for (int kc = 0; kc < 4; ++kc) {
        const float* ap = xin + (size_t)arow * 128 + kc * 32 + lg * 8;
        const float4 u0 = *(const float4*)(ap);
        const float4 u1 = *(const float4*)(ap + 4);
        const float av[8] = {u0.x, u0.y, u0.z, u0.w, u1.x, u1.y, u1.z, u1.w};
        half8v xh, xl;
#pragma unroll
        for (int i = 0; i < 8; ++i) {
            const _Float16 h = (_Float16)av[i];
            xh[i] = h;
            xl[i] = (_Float16)(av[i] - (float)h);
        }
        const int kofs = (kc * 64 + lg * 16) ^ sw;
#pragma unroll
        for (int nt = 0; nt < 8; ++nt) {
            const int row = nt * 16 + ln;
            const half8v bF = *(const half8v*)(wg + row * 256 + kofs);
            const half8v bS = *(const half8v*)(wg + 32768 + row * 256 + kofs);
            accF[nt] = __builtin_amdgcn_mfma_f32_16x16x32_f16(xh, bF, accF[nt], 0, 0, 0);
            accF[nt] = __builtin_amdgcn_mfma_f32_16x16x32_f16(xl, bF, accF[nt], 0, 0, 0);
            accS[nt] = __builtin_amdgcn_mfma_f32_16x16x32_f16(xh, bS, accS[nt], 0, 0, 0);
            accS[nt] = __builtin_amdgcn_mfma_f32_16x16x32_f16(xl, bS, accS[nt], 0, 0, 0);
        }
    }

    unsigned int* Tw = t ? Tsw : Tdw;
#pragma unroll
    for (int nt = 0; nt < 8; ++nt) {
        const int ch = nt * 16 + ln;
        float addF = 0.f, addS = 0.f;
        if (t == 0) { addF = bfv[ch]; addS = bsv[ch]; }
#pragma unroll
        for (int r = 0; r < 4; ++r) {
            const int node = nb + lg * 4 + r;
            if (node < NN) {
                const __half2 p = __floats2half2_rn(accF[nt][r] + addF, accS[nt][r] + addS);
                Tw[(size_t)node * 128 + ch] = *(const unsigned int*)&p;
            }
        }
    }
}

// ================= fused edge kernel: MFMA f16, store interior runs, atomic boundaries =================
template<int PERM>
__global__ __launch_bounds__(256, 4) void k_edge6(
    const unsigned int* __restrict__ Tdw, const unsigned int* __restrict__ Tsw,
    const unsigned short* __restrict__ Wimg,
    const int* __restrict__ seid, const int2* __restrict__ sds,
    const float* __restrict__ ea, const _Float16* __restrict__ eas,
    float* __restrict__ agg)
{
    __shared__ short Wt[16384];   // 32 KB edge-slice image
    const int tid = threadIdx.x;
    {
        const int4* src = (const int4*)Wimg;
        int4* dst = (int4*)Wt;
        for (int j = tid; j < 2048; j += 256) dst[j] = src[j];
    }
    __syncthreads();

    const int lane = tid & 63;
    const int ln = lane & 15, lg = lane >> 4;
    const int gw = blockIdx.x * 4 + (tid >> 6);
    const int nwv = gridDim.x * 4;
    const int sw = (ln & 7) << 4;

    const int NCH = NE / 16;
    const int lo = (int)(((long long)gw * NCH) / nwv);
    const int hi = (int)(((long long)(gw + 1) * NCH) / nwv);
    if (lo >= hi) return;
    const int wlo = lo * 16;
    const int Q = (hi - lo) * 4;       // edges per lane-group (contiguous)
    const int NT = hi - lo;

    const int abase = wlo + (ln >> 2) * Q + (ln & 3);  // A-row edge (+ t*4)
    const int gbase = wlo + lg * Q;                    // C-group edge base (+ t*4 + r)

    float pend[8];
    float2 gdc[8];
    int pdn = -1;
    bool first = true;
#pragma unroll
    for (int nt = 0; nt < 8; ++nt) { pend[nt] = 0.f; gdc[nt] = make_float2(0.f, 0.f); }

    const char* wb = (const char*)Wt;

    for (int t = 0; t < NT; ++t) {
        const int e4 = gbase + t * 4;
        const int4 p01 = *(const int4*)(sds + e4);
        const int4 p23 = *(const int4*)(sds + e4 + 2);
        const int sn[4] = {p01.x, p01.z, p23.x, p23.z};
        const int dn[4] = {p01.y, p01.w, p23.y, p23.w};

        // A fragments
        half8v a0, a1;
        if (PERM) {
            const _Float16* ap = eas + (size_t)(abase + t * 4) * 64;
            a0 = *(const half8v*)(ap + lg * 8);
            a1 = *(const half8v*)(ap + 32 + lg * 8);
        } else {
            const int eln = seid[abase + t * 4];
            const float* ap = ea + (size_t)eln * 64 + lg * 8;
            const float4 v0 = *(const float4*)(ap);
            const float4 v1 = *(const float4*)(ap + 4);
            const float4 v2 = *(const float4*)(ap + 32);
            const float4 v3 = *(const float4*)(ap + 36);
            const float av0[8] = {v0.x, v0.y, v0.z, v0.w, v1.x, v1.y, v1.z, v1.w};
            const float av1[8] = {v2.x, v2.y, v2.z, v2.w, v3.x, v3.y, v3.z, v3.w};
#pragma unroll
            for (int i = 0; i < 8; ++i) { a0[i] = (_Float16)av0[i]; a1[i] = (_Float16)av1[i]; }
        }

        // Tsrc gathers (issued before MFMA)
        unsigned int gsw[4][8];
#pragma unroll
        for (int r = 0; r < 4; ++r)
#pragma unroll
            for (int nt = 0; nt < 8; ++nt)
                gsw[r][nt] = Tsw[(size_t)sn[r] * 128 + nt * 16 + ln];

        f32x4 accf[8], accs[8];
        const f32x4 zz = {0.f, 0.f, 0.f, 0.f};
#pragma unroll
        for (int nt = 0; nt < 8; ++nt) { accf[nt] = zz; accs[nt] = zz; }

#pragma unroll
        for (int nt = 0; nt < 8; ++nt) {
            const int rowf = nt * 16 + ln;
            const half8v bf0 = *(const half8v*)(wb + rowf * 128 + ((lg * 16) ^ sw));
            const half8v bf1 = *(const half8v*)(wb + rowf * 128 + ((64 + lg * 16) ^ sw));
            const half8v bs0 = *(const half8v*)(wb + (128 + rowf) * 128 + ((lg * 16) ^ sw));
            const half8v bs1 = *(const half8v*)(wb + (128 + rowf) * 128 + ((64 + lg * 16) ^ sw));
            accf[nt] = __builtin_amdgcn_mfma_f32_16x16x32_f16(a0, bf0, accf[nt], 0, 0, 0);
            accf[nt] = __builtin_amdgcn_mfma_f32_16x16x32_f16(a1, bf1, accf[nt], 0, 0, 0);
            accs[nt] = __builtin_amdgcn_mfma_f32_16x16x32_f16(a0, bs0, accs[nt], 0, 0, 0);
            accs[nt] = __builtin_amdgcn_mfma_f32_16x16x32_f16(a1, bs1, accs[nt], 0, 0, 0);
        }

        // epilogue: runs carried across tiles; interior runs = plain store
#pragma unroll
        for (int r = 0; r < 4; ++r) {
            if (dn[r] != pdn) {
                if (pdn >= 0) {
                    float* xo = agg + (size_t)pdn * 128 + ln;
                    if (first) {
#pragma unroll
                        for (int nt = 0; nt < 8; ++nt) atomicAdd(xo + nt * 16, pend[nt]);
                    } else {
#pragma unroll
                        for (int nt = 0; nt < 8; ++nt) xo[nt * 16] = pend[nt];
                    }
                    first = false;
                }
                pdn = dn[r];
#pragma unroll
                for (int nt = 0; nt < 8; ++nt) {
                    const __half2 hd = *(const __half2*)&Tdw[(size_t)pdn * 128 + nt * 16 + ln];
                    gdc[nt] = __half22float2(hd);
                    pend[nt] = 0.f;
                }
            }
#pragma unroll
            for (int nt = 0; nt < 8; ++nt) {
                const __half2 hw = *(const __half2*)&gsw[r][nt];
                const float2 gs = __half22float2(hw);
                const float F = accf[nt][r] + gdc[nt].x + gs.x;
                const float S = accs[nt][r] + gdc[nt].y + gs.y;
                pend[nt] += sigm(F) * sofp(S);
            }
        }
    }
    // final run touches the range boundary: atomic
    {
        float* xo = agg + (size_t)pdn * 128 + ln;
#pragma unroll
        for (int nt = 0; nt < 8; ++nt) atomicAdd(xo + nt * 16, pend[nt]);
    }
}

// ================= batchnorm (fused with x+agg) =================
__global__ __launch_bounds__(256) void k_bn_stats2(const float* __restrict__ xv, const float* __restrict__ agg,
                                                   float* __restrict__ stats)
{
    const int c = threadIdx.x & 127;
    const int half = threadIdx.x >> 7;
    float s = 0.0f, q = 0.0f;
    for (int r = blockIdx.x * 2 + half; r < NN; r += gridDim.x * 2) {
        const float v = xv[(size_t)r * 128 + c] + agg[(size_t)r * 128 + c];
        s += v; q = fmaf(v, v, q);
    }
    __shared__ float sh[2][128];
    if (half) { sh[0][c] = s; sh[1][c] = q; }
    __syncthreads();
    if (!half) {
        s += sh[0][c]; q += sh[1][c];
        atomicAdd(&stats[c], s);
        atomicAdd(&stats[128 + c], q);
    }
}

__global__ void k_bn_finalize(const float* __restrict__ stats, const float* __restrict__ g,
                              const float* __restrict__ be, float* __restrict__ ab)
{
    const int c = threadIdx.x;
    const float mu = stats[c] * (1.0f / NN);
    const float var = stats[128 + c] * (1.0f / NN) - mu * mu;
    const float a = g[c] * rsqrtf(var + BN_EPS);
    ab[c] = a;
    ab[128 + c] = fmaf(-mu, a, be[c]);
}

__global__ __launch_bounds__(256) void k_bn_apply2(
    const float* __restrict__ xv, const float* __restrict__ agg,
    const float* __restrict__ ab, float* __restrict__ xo)
{
    const size_t i = (size_t)blockIdx.x * 256 + threadIdx.x;
    const int c = ((int)i & 31) * 4;
    float4 v = ((const float4*)xv)[i];
    const float4 g = ((const float4*)agg)[i];
    v.x = fmaf(v.x + g.x, ab[c],     ab[128 + c]);
    v.y = fmaf(v.y + g.y, ab[c + 1], ab[128 + c + 1]);
    v.z = fmaf(v.z + g.z, ab[c + 2], ab[128 + c + 2]);
    v.w = fmaf(v.w + g.w, ab[c + 3], ab[128 + c + 3]);
    ((float4*)xo)[i] = v;
}

__global__ __launch_bounds__(256) void k_bn_apply_pool2(
    const float* __restrict__ xv, const float* __restrict__ agg, const float* __restrict__ ab,
    const int* __restrict__ bat, float* __restrict__ pool, float* __restrict__ cnt)
{
    const int c = threadIdx.x & 127;
    const int half = threadIdx.x >> 7;
    const float a = ab[c], b = ab[128 + c];
    for (int r = blockIdx.x * 2 + half; r < NN; r += gridDim.x * 2) {
        const int g = bat[r];
        const float v = xv[(size_t)r * 128 + c] + agg[(size_t)r * 128 + c];
        atomicAdd(&pool[(size_t)g * 128 + c], fmaf(v, a, b));
        if (c == 0) atomicAdd(&cnt[g], 1.0f);
    }
}

__global__ __launch_bounds__(256) void k_pool_fin(const float* __restrict__ pool, const float* __restrict__ cnt,
                                                  float* __restrict__ out)
{
    const int i = blockIdx.x * 256 + threadIdx.x;
    out[i] = pool[i] / fmaxf(cnt[i >> 7], 1.0f);
}

extern "C" void kernel_launch(void* const* d_in, const int* in_sizes, int n_in,
                              void* d_out, int out_size, void* d_ws, size_t ws_size,
                              hipStream_t stream)
{
    const float* x   = (const float*)d_in[0];
    const int*   ei  = (const int*)d_in[1];
    const float* ea  = (const float*)d_in[2];
    const int*   bat = (const int*)d_in[3];
    const float* Wf[2] = { (const float*)d_in[4],  (const float*)d_in[10] };
    const float* bf[2] = { (const float*)d_in[5],  (const float*)d_in[11] };
    const float* Ws[2] = { (const float*)d_in[6],  (const float*)d_in[12] };
    const float* bs[2] = { (const float*)d_in[7],  (const float*)d_in[13] };
    const float* gm[2] = { (const float*)d_in[8],  (const float*)d_in[14] };
    const float* be[2] = { (const float*)d_in[9],  (const float*)d_in[15] };

    char* wsp = (char*)d_ws;
    unsigned int* Tdw = (unsigned int*)wsp;                 // [N][128] packed half2 (f,s)
    unsigned int* Tsw = Tdw + (size_t)NN * 128;             // [N][128] packed half2
    float* agg    = (float*)(Tsw + (size_t)NN * 128);       // [N][128] fp32
    float* xb1    = agg + (size_t)NN * 128;                 // [N][128] fp32
    float* stats0 = xb1 + (size_t)NN * 128;                 // 256
    float* stats1 = stats0 + 256;                           // 256
    float* ab     = stats1 + 256;                           // 256
    float* pool   = ab + 256;                               // [G][128]
    float* cnt    = pool + (size_t)NG * 128;                // G
    int* hist    = (int*)(cnt + NG);                        // NNP
    int* partial = hist + NNP;                              // 256
    int* topoff  = partial + 256;                           // 256
    int* cursor  = topoff + 256;                            // NN
    int* seid    = cursor + NN;                             // NE
    int2* sds    = (int2*)(seid + NE);                      // NE int2
    unsigned short* Wn16 = (unsigned short*)(sds + NE);     // 131072 ushorts
    unsigned short* We16 = Wn16 + 131072;                   // 32768 ushorts
    _Float16* eas = (_Float16*)(We16 + 32768);              // NE*64 halves (102.4 MB)

    const size_t need = (size_t)((char*)(eas + (size_t)NE * 64) - (char*)d_ws);
    const bool perm = ws_size >= need;

    hipMemsetAsync(pool, 0, ((size_t)NG * 128 + NG) * sizeof(float), stream);
    hipMemsetAsync(hist, 0, NNP * sizeof(int), stream);
    hipMemsetAsync(stats0, 0, 512 * sizeof(float), stream);

    // one-time: W conversion + dst-sorted edge permutation (+ ea perm/cvt)
    k_wcvt<<<640, 256, 0, stream>>>(Wf[0], Ws[0], Wf[1], Ws[1], Wn16, We16);
    k_hist<<<(NE + 255) / 256, 256, 0, stream>>>(ei, hist);
    k_scan_partial<<<196, 256, 0, stream>>>(hist, partial);
    k_scan_top<<<1, 256, 0, stream>>>(partial, topoff);
    k_scan_final<<<196, 256, 0, stream>>>(hist, topoff, cursor);
    k_scatter<<<(NE + 255) / 256, 256, 0, stream>>>(ei, cursor, seid, sds);
    if (perm) k_eperm<<<NE / 16, 256, 0, stream>>>(seid, ea, eas);

    // ---- layer 1 ----
    k_nl<<<dim3(782, 2), 256, 0, stream>>>(x, Wn16, bf[0], bs[0], Tdw, Tsw);
    hipMemsetAsync(agg, 0, (size_t)NN * 128 * sizeof(float), stream);
    if (perm) k_edge6<1><<<1024, 256, 0, stream>>>(Tdw, Tsw, We16, seid, sds, ea, eas, agg);
    else      k_edge6<0><<<1024, 256, 0, stream>>>(Tdw, Tsw, We16, seid, sds, ea, eas, agg);
    k_bn_stats2<<<256, 256, 0, stream>>>(x, agg, stats0);
    k_bn_finalize<<<1, 128, 0, stream>>>(stats0, gm[0], be[0], ab);
    k_bn_apply2<<<6250, 256, 0, stream>>>(x, agg, ab, xb1);   // xb1 = BN(x + agg0)

    // ---- layer 2 ----
    k_nl<<<dim3(782, 2), 256, 0, stream>>>(xb1, Wn16 + 65536, bf[1], bs[1], Tdw, Tsw);
    hipMemsetAsync(agg, 0, (size_t)NN * 128 * sizeof(float), stream);
    if (perm) k_edge6<1><<<1024, 256, 0, stream>>>(Tdw, Tsw, We16 + 16384, seid, sds, ea, eas, agg);
    else      k_edge6<0><<<1024, 256, 0, stream>>>(Tdw, Tsw, We16 + 16384, seid, sds, ea, eas, agg);
    k_bn_stats2<<<256, 256, 0, stream>>>(xb1, agg, stats1);
    k_bn_finalize<<<1, 128, 0, stream>>>(stats1, gm[1], be[1], ab);
    k_bn_apply_pool2<<<256, 256, 0, stream>>>(xb1, agg, ab, bat, pool, cnt);

    k_pool_fin<<<NG * 128 / 256, 256, 0, stream>>>(pool, cnt, (float*)d_out);
}